// Round 16
// baseline (395.708 us; speedup 1.0000x reference)
//
#include <hip/hip_runtime.h>
#include <math.h>

#define N_U 30000
#define N_I 15000
#define N_TOT 45000
#define D 64
#define NNZ 480000
#define B 2048
#define INV_TEMP 5.0f
#define LOG_EPS -18.420680743952367f
#define NEG_SLOPE 0.2f
#define LAMBDA1 0.2f
#define LAMBDA2 1e-7f

// MFMA-lse config (r16): EQUAL-WORK splits — RSP=352 rows for both sides so every block
// does ~22 iterations (U: 86 splits, I: 43; 516 blocks total). r15's dim3(4,64,2) paired
// each CU with one 30-iter U-block and one 15-iter I-block -> 15-iter solo tail at half
// occupancy on this latency-bound kernel.
#define NSP_U 86
#define NSP_I 43
#define RSP 352
#define NBLK_U (4 * NSP_U)   // 344
#define NBLK (4 * (NSP_U + NSP_I))  // 516
#define PAD_U 30016
#define PAD_I 15040
#define SCALE_LOG2 7.2134752044448170f
#define LN2F 0.6931471805599453f
#define NREGP 2813  // k_init grid size = (N_TOT*16+255)/256

typedef __attribute__((ext_vector_type(8))) short short8;
typedef __attribute__((ext_vector_type(4))) float f32x4;

__device__ inline float wred(float v) {
#pragma unroll
  for (int o = 32; o > 0; o >>= 1) v += __shfl_down(v, o, 64);
  return v;
}

__device__ inline float leaky(float v) { return (v >= 0.f) ? v : NEG_SLOPE * v; }

__device__ inline void atomMaxF(float* a, float v) {
  if (v >= 0.f) atomicMax((int*)a, __float_as_int(v));
  else atomicMin((unsigned int*)a, __float_as_uint(v));
}

__device__ inline unsigned short f2bf(float x) {
  unsigned u = __float_as_uint(x);
  unsigned r = u + 0x7FFFu + ((u >> 16) & 1u);
  return (unsigned short)(r >> 16);
}
__device__ inline float bf2f(unsigned short h) {
  return __uint_as_float(((unsigned)h) << 16);
}

// ---------------- init: float4-vectorized; interleaved bf16 mirror; NO sE/sG writes (both
// deferred to last layer, bit-exact); fused per-block L2-reg partial sum ----------------
__global__ void k_init(const float* __restrict__ Eu0, const float* __restrict__ Ei0,
                       float* fU, float* fI,
                       unsigned short* gU, unsigned short* gI,
                       int* deg, float* acc,
                       float* __restrict__ regp) {
  __shared__ float red[4];
  int t = blockIdx.x * 256 + threadIdx.x;  // t in [0, N_TOT*16)
  if (t < 20) acc[t] = (t >= 8 && t < 16) ? -INFINITY : 0.f;
  if (t < N_I) deg[t] = 0;
  int n = t >> 4, q = t & 15;
  float s = 0.f;
  if (n < N_U) {
    float4 v = ((const float4*)Eu0)[t];
    ((float4*)(fU + (size_t)n * 128))[q] = v;
    uint4 gv = {(unsigned)f2bf(v.x), (unsigned)f2bf(v.y), (unsigned)f2bf(v.z), (unsigned)f2bf(v.w)};
    ((uint4*)(gU + (size_t)n * 128))[q] = gv;
    s = v.x * v.x + v.y * v.y + v.z * v.z + v.w * v.w;
  } else if (n < N_TOT) {
    int j = t - N_U * 16;
    int ni = n - N_U;
    float4 v = ((const float4*)Ei0)[j];
    ((float4*)(fI + (size_t)ni * 128))[q] = v;
    uint4 gv = {(unsigned)f2bf(v.x), (unsigned)f2bf(v.y), (unsigned)f2bf(v.z), (unsigned)f2bf(v.w)};
    ((uint4*)(gI + (size_t)ni * 128))[q] = gv;
    s = v.x * v.x + v.y * v.y + v.z * v.z + v.w * v.w;
  }
  s = wred(s);
  int lane = threadIdx.x & 63, wv = threadIdx.x >> 6;
  if (lane == 0) red[wv] = s;
  __syncthreads();
  if (threadIdx.x == 0)
    regp[blockIdx.x] = red[0] + red[1] + red[2] + red[3];
}

// ---------------- CSR build over item side ----------------
__global__ void k_deg(const int* __restrict__ ii, int* deg) {
  int e = blockIdx.x * 256 + threadIdx.x;
  if (e < NNZ) atomicAdd(&deg[ii[e]], 1);
}

// shuffle-based scan: 2 barriers, deg cached in registers (bit-exact int ops)
__global__ void k_scan(const int* __restrict__ deg, int* rowptr, int* cursor) {
  __shared__ int wtot[16], woff[16];
  const int CHUNK = 15;
  int tid = threadIdx.x, lane = tid & 63, wv = tid >> 6;
  int base = tid * CHUNK;
  int dv[CHUNK];
  int s = 0;
#pragma unroll
  for (int k = 0; k < CHUNK; k++) {
    int idx = base + k;
    dv[k] = (idx < N_I) ? deg[idx] : 0;
    s += dv[k];
  }
  int v = s;
#pragma unroll
  for (int o = 1; o < 64; o <<= 1) {
    int x = __shfl_up(v, o, 64);
    if (lane >= o) v += x;
  }
  if (lane == 63) wtot[wv] = v;
  __syncthreads();
  if (tid < 16) {
    int w = wtot[tid];
    int iv = w;
#pragma unroll
    for (int o = 1; o < 16; o <<= 1) {
      int x = __shfl_up(iv, o, 16);
      if (tid >= o) iv += x;
    }
    woff[tid] = iv - w;
  }
  __syncthreads();
  int excl = (v - s) + woff[wv];
#pragma unroll
  for (int k = 0; k < CHUNK; k++) {
    int idx = base + k;
    if (idx < N_I) {
      rowptr[idx] = excl;
      cursor[idx] = excl;
      excl += dv[k];
    }
  }
  if (tid == 1023) rowptr[N_I] = excl;
}

__global__ void k_fill(const int* __restrict__ ii, const float* __restrict__ vals,
                       int* cursor, int* u_srt, float* v_srt) {
  int e = blockIdx.x * 256 + threadIdx.x;
  if (e < NNZ) {
    int pos = atomicAdd(&cursor[ii[e]], 1);
    u_srt[pos] = e >> 4;
    v_srt[pos] = vals[e];
  }
}

// ---------------- GAT: feat = E @ W into fused[64:128] (fp32) + interleaved bf16 mirror, el/er ----------------
__global__ void k_feat(float* __restrict__ fU, float* __restrict__ fI,
                       unsigned short* __restrict__ gU, unsigned short* __restrict__ gI,
                       const float* __restrict__ W, const float* __restrict__ al,
                       const float* __restrict__ ar,
                       float* __restrict__ el, float* __restrict__ er) {
  __shared__ float Ws[64 * 64];
  __shared__ float hs[16][64];
  int tid = threadIdx.x;
  for (int t = tid; t < 1024; t += 256) ((float4*)Ws)[t] = ((const float4*)W)[t];
  int g = tid >> 6, c = tid & 63;
  int n0 = blockIdx.x * 16 + g * 4;
  float* rows[4];
  unsigned short* grows[4];
#pragma unroll
  for (int j = 0; j < 4; j++) {
    int node = n0 + j;
    rows[j] = nullptr; grows[j] = nullptr;
    if (node < N_TOT) {
      if (node < N_U) {
        rows[j] = fU + (size_t)node * 128;
        grows[j] = gU + (size_t)node * 128;
      } else {
        rows[j] = fI + (size_t)(node - N_U) * 128;
        grows[j] = gI + (size_t)(node - N_U) * 128;
      }
      hs[g * 4 + j][c] = rows[j][c];
    }
  }
  __syncthreads();
  float a0 = 0.f, a1 = 0.f, a2 = 0.f, a3 = 0.f;
#pragma unroll 8
  for (int k = 0; k < 64; ++k) {
    float w = Ws[k * 64 + c];
    a0 = fmaf(hs[g * 4 + 0][k], w, a0);
    a1 = fmaf(hs[g * 4 + 1][k], w, a1);
    a2 = fmaf(hs[g * 4 + 2][k], w, a2);
    a3 = fmaf(hs[g * 4 + 3][k], w, a3);
  }
  float accs[4] = {a0, a1, a2, a3};
  float alc = al[c], arc = ar[c];
#pragma unroll
  for (int j = 0; j < 4; j++) {
    int node = n0 + j;
    if (node >= N_TOT) continue;
    rows[j][64 + c] = accs[j];
    grows[j][2 * c + 1] = f2bf(accs[j]);
    float pl = accs[j] * alc;
    float pr = accs[j] * arc;
#pragma unroll
    for (int o = 8; o >= 1; o >>= 1) {
      pl += __shfl_down(pl, o, 16);
      pr += __shfl_down(pr, o, 16);
    }
    if ((c & 15) == 0) {
      el[node * 4 + (c >> 4)] = pl;
      er[node * 4 + (c >> 4)] = pr;
    }
  }
}

// ---------------- per-head global max of el (separate kernel: few atomics; r7 lesson) ----------------
__global__ void k_elmax(const float* __restrict__ el, float* __restrict__ dst) {
  __shared__ float red[4][4];
  int tid = threadIdx.x;
  int lane = tid & 63, wv = tid >> 6;
  float mx = -INFINITY;
  for (int t = blockIdx.x * 256 + tid; t < N_TOT * 4; t += 64 * 256)
    mx = fmaxf(mx, el[t]);
#pragma unroll
  for (int o = 4; o < 64; o <<= 1) mx = fmaxf(mx, __shfl_xor(mx, o, 64));
  if (lane < 4) red[wv][lane] = mx;
  __syncthreads();
  if (tid < 4) {
    float m2 = fmaxf(fmaxf(red[0][tid], red[1][tid]), fmaxf(red[2][tid], red[3][tid]));
    atomMaxF(dst + tid, m2);
  }
}

// ---------------- fused graph layer ----------------
// r10: exp-dedup via shfl + interleaved-mirror gathers.
// r13: deferred sE — last layer computes s_final=(E0+selfrow)+e_new (bit-exact).
// r14: deferred sG — layer1 stores g1; last layer sG=(E0+g1)+g2; dead-store elim on last layer.
__global__ void k_layer(const float* __restrict__ fU_cur, const float* __restrict__ fI_cur,
                        const unsigned short* __restrict__ gU_cur,
                        const unsigned short* __restrict__ gI_cur,
                        const float* __restrict__ el, const float* __restrict__ er,
                        const float* __restrict__ vals, const int* __restrict__ ii,
                        const int* __restrict__ rowptr, const int* __restrict__ u_srt,
                        const float* __restrict__ v_srt,
                        const float* __restrict__ elmx,
                        const float* __restrict__ E0u, const float* __restrict__ E0i,
                        float* __restrict__ fU_nxt, float* __restrict__ fI_nxt,
                        unsigned short* __restrict__ gU_nxt, unsigned short* __restrict__ gI_nxt,
                        float* __restrict__ sEu, float* __restrict__ sEi,
                        float* __restrict__ sGu, float* __restrict__ sGi,
                        unsigned short* __restrict__ EuH, unsigned short* __restrict__ EuL,
                        unsigned short* __restrict__ EiH, unsigned short* __restrict__ EiL,
                        float* __restrict__ normU, float* __restrict__ normI) {
  int t = blockIdx.x * 256 + threadIdx.x;
  int node = t >> 6, c = t & 63;
  if (node >= N_TOT) return;
  int h = c >> 4;
  int k2 = c & 15;

  if (node < N_U) {
    int u = node;
    float eru = er[u * 4 + h];
    float m = leaky(elmx[h] + eru);
    const float* selfrow = fU_cur + (size_t)u * 128;
    float aself = __expf(leaky(el[u * 4 + h] + eru) - m);

    int idx[16]; float vv[16];
#pragma unroll
    for (int k = 0; k < 16; k++) { idx[k] = ii[u * 16 + k]; vv[k] = vals[u * 16 + k]; }

    float ev = __expf(leaky(el[(ii[u * 16 + k2] + N_U) * 4 + h] + eru) - m);
    float av[16];
#pragma unroll
    for (int k = 0; k < 16; k++)
      av[k] = __shfl(ev, (c & 48) | k, 64);

    float den = aself;
#pragma unroll
    for (int k = 0; k < 16; k++) den += av[k];

    float o0 = aself * selfrow[64 + c], o1 = 0.f;
    float z0 = 0.f, z1 = 0.f;
#pragma unroll
    for (int k = 0; k < 16; k += 2) {
      unsigned wA = *(const unsigned*)(gI_cur + (size_t)idx[k] * 128 + 2 * c);
      unsigned wB = *(const unsigned*)(gI_cur + (size_t)idx[k + 1] * 128 + 2 * c);
      float eA = __uint_as_float(wA << 16), fA = __uint_as_float(wA & 0xFFFF0000u);
      float eB = __uint_as_float(wB << 16), fB = __uint_as_float(wB & 0xFFFF0000u);
      z0 = fmaf(vv[k], eA, z0);
      z1 = fmaf(vv[k + 1], eB, z1);
      o0 = fmaf(av[k], fA, o0);
      o1 = fmaf(av[k + 1], fB, o1);
    }
    float o = (o0 + o1) / den;
    float g = (o > 0.f) ? o : expm1f(o);
    float e_new = selfrow[c] + z0 + z1;
    size_t off = (size_t)u * D + c;
    if (EuH) {
      float e0v = E0u[off];
      float s_final = (e0v + selfrow[c]) + e_new;
      sEu[off] = s_final;
      sGu[off] = (e0v + sGu[off]) + g;
      unsigned short hi = f2bf(s_final);
      EuH[off] = hi;
      EuL[off] = f2bf(s_final - bf2f(hi));
      float n2 = wred(s_final * s_final);
      if (c == 0) normU[u] = n2;
    } else {
      fU_nxt[(size_t)u * 128 + c] = e_new;
      gU_nxt[(size_t)u * 128 + 2 * c] = f2bf(e_new);
      sGu[off] = g;
    }
  } else {
    int i = node - N_U;
    float eri = er[node * 4 + h];
    float m = leaky(elmx[h] + eri);
    const float* selfrow = fI_cur + (size_t)i * 128;
    float aself = __expf(leaky(el[node * 4 + h] + eri) - m);
    float den0 = aself, den1 = 0.f;
    float o0 = aself * selfrow[64 + c], o1 = 0.f;
    float z0 = 0.f, z1 = 0.f;
    int r0 = rowptr[i], r1 = rowptr[i + 1];
    for (int rb = r0; rb < r1; rb += 16) {
      int cnt = min(16, r1 - rb);
      int rr = rb + (k2 < cnt ? k2 : cnt - 1);
      float ev = __expf(leaky(el[u_srt[rr] * 4 + h] + eri) - m);
      int k = 0;
      for (; k + 3 < cnt; k += 4) {
        int u0 = u_srt[rb + k], u1 = u_srt[rb + k + 1], u2 = u_srt[rb + k + 2], u3 = u_srt[rb + k + 3];
        float v0 = v_srt[rb + k], v1 = v_srt[rb + k + 1], v2 = v_srt[rb + k + 2], v3 = v_srt[rb + k + 3];
        float a0 = __shfl(ev, (c & 48) | k, 64);
        float a1 = __shfl(ev, (c & 48) | (k + 1), 64);
        float a2 = __shfl(ev, (c & 48) | (k + 2), 64);
        float a3 = __shfl(ev, (c & 48) | (k + 3), 64);
        unsigned w0 = *(const unsigned*)(gU_cur + (size_t)u0 * 128 + 2 * c);
        unsigned w1 = *(const unsigned*)(gU_cur + (size_t)u1 * 128 + 2 * c);
        unsigned w2 = *(const unsigned*)(gU_cur + (size_t)u2 * 128 + 2 * c);
        unsigned w3 = *(const unsigned*)(gU_cur + (size_t)u3 * 128 + 2 * c);
        float e0 = __uint_as_float(w0 << 16), f0 = __uint_as_float(w0 & 0xFFFF0000u);
        float e1 = __uint_as_float(w1 << 16), f1 = __uint_as_float(w1 & 0xFFFF0000u);
        float e2 = __uint_as_float(w2 << 16), f2 = __uint_as_float(w2 & 0xFFFF0000u);
        float e3 = __uint_as_float(w3 << 16), f3 = __uint_as_float(w3 & 0xFFFF0000u);
        z0 = fmaf(v0, e0, z0); z1 = fmaf(v1, e1, z1);
        z0 = fmaf(v2, e2, z0); z1 = fmaf(v3, e3, z1);
        den0 += a0 + a2; den1 += a1 + a3;
        o0 = fmaf(a0, f0, o0); o1 = fmaf(a1, f1, o1);
        o0 = fmaf(a2, f2, o0); o1 = fmaf(a3, f3, o1);
      }
      for (; k < cnt; k++) {
        int u0 = u_srt[rb + k];
        float v0 = v_srt[rb + k];
        float a0 = __shfl(ev, (c & 48) | k, 64);
        unsigned w0 = *(const unsigned*)(gU_cur + (size_t)u0 * 128 + 2 * c);
        float e0 = __uint_as_float(w0 << 16), f0 = __uint_as_float(w0 & 0xFFFF0000u);
        z0 = fmaf(v0, e0, z0);
        den0 += a0;
        o0 = fmaf(a0, f0, o0);
      }
    }
    float o = (o0 + o1) / (den0 + den1);
    float g = (o > 0.f) ? o : expm1f(o);
    float e_new = selfrow[c] + z0 + z1;
    size_t off = (size_t)i * D + c;
    if (EiH) {
      float e0v = E0i[off];
      float s_final = (e0v + selfrow[c]) + e_new;
      sEi[off] = s_final;
      sGi[off] = (e0v + sGi[off]) + g;
      unsigned short hi = f2bf(s_final);
      EiH[off] = hi;
      EiL[off] = f2bf(s_final - bf2f(hi));
      float n2 = wred(s_final * s_final);
      if (c == 0) normI[i] = n2;
    } else {
      fI_nxt[(size_t)i * 128 + c] = e_new;
      gI_nxt[(size_t)i * 128 + 2 * c] = f2bf(e_new);
      sGi[off] = g;
    }
  }
}

// ---------------- max row-norm reduce + L2 reg reduce (reads per-block partials from k_init) ----------------
__global__ void k_normreg(const float* __restrict__ nU, const float* __restrict__ nI,
                          const float* __restrict__ regp,
                          float* __restrict__ acc) {
  __shared__ float red[4][3];
  int tid = threadIdx.x;
  int lane = tid & 63, wv = tid >> 6;
  float mu = 0.f, mi = 0.f, s = 0.f;
  for (int t = blockIdx.x * 256 + tid; t < N_U; t += 128 * 256) mu = fmaxf(mu, nU[t]);
  for (int t = blockIdx.x * 256 + tid; t < N_I; t += 128 * 256) mi = fmaxf(mi, nI[t]);
  for (int t = blockIdx.x * 256 + tid; t < NREGP; t += 128 * 256) s += regp[t];
#pragma unroll
  for (int o = 32; o > 0; o >>= 1) {
    mu = fmaxf(mu, __shfl_down(mu, o, 64));
    mi = fmaxf(mi, __shfl_down(mi, o, 64));
    s += __shfl_down(s, o, 64);
  }
  if (lane == 0) { red[wv][0] = mu; red[wv][1] = mi; red[wv][2] = s; }
  __syncthreads();
  if (tid == 0) {
    float a = fmaxf(fmaxf(red[0][0], red[1][0]), fmaxf(red[2][0], red[3][0]));
    float b = fmaxf(fmaxf(red[0][1], red[1][1]), fmaxf(red[2][1], red[3][1]));
    float ssum = red[0][2] + red[1][2] + red[2][2] + red[3][2];
    atomMaxF(acc + 6, a);
    atomMaxF(acc + 7, b);
    unsafeAtomicAdd(acc + 5, ssum);
  }
}

// ---------------- gathered queries: pre-scaled split-bf16 + Cauchy-Schwarz offset M0 ----------------
__global__ void k_cvt_q(const float* __restrict__ sGu, const float* __restrict__ sGi,
                        const int* __restrict__ uids, const int* __restrict__ iids,
                        unsigned short* __restrict__ QuH, unsigned short* __restrict__ QuL,
                        unsigned short* __restrict__ QiH, unsigned short* __restrict__ QiL,
                        const float* __restrict__ acc,
                        float* __restrict__ M0u, float* __restrict__ M0i) {
  int lane = threadIdx.x & 63, wv = threadIdx.x >> 6;
  int row = blockIdx.x * 4 + wv;
  int side = row >> 11;
  int b = row & (B - 1);
  int id = side ? iids[b] : uids[b];
  float x = (side ? sGi : sGu)[(size_t)id * 64 + lane] * SCALE_LOG2;
  unsigned short hi = f2bf(x);
  unsigned short lo = f2bf(x - bf2f(hi));
  if (side) { QiH[(size_t)b * 64 + lane] = hi; QiL[(size_t)b * 64 + lane] = lo; }
  else      { QuH[(size_t)b * 64 + lane] = hi; QuL[(size_t)b * 64 + lane] = lo; }
  float n2 = wred(x * x);
  if (lane == 0) {
    float en2 = side ? acc[7] : acc[6];
    float M0 = sqrtf(n2) * sqrtf(en2) * 1.01f + 1.0f;
    (side ? M0i : M0u)[b] = M0;
  }
}

// ---------------- MFMA logsumexp: r2-exact inner loop; equal-work 1-D grid (r16) ----------------
// (256,2)+t=8+depth-1 proven r2-r6. 516 blocks, each ~22 iters: U wid<344, I wid>=344;
// split=wid>>2, qb=wid&3 (consecutive blocks share a split, as before).
__global__ __launch_bounds__(256, 2) void k_lse_mfma(
    const unsigned short* __restrict__ QuH, const unsigned short* __restrict__ QuL,
    const unsigned short* __restrict__ EuHp, const unsigned short* __restrict__ EuLp,
    const unsigned short* __restrict__ QiH, const unsigned short* __restrict__ QiL,
    const unsigned short* __restrict__ EiHp, const unsigned short* __restrict__ EiLp,
    const float* __restrict__ M0u, const float* __restrict__ M0i,
    float* __restrict__ psU, float* __restrict__ psI) {
  int wid = blockIdx.x;
  int z = (wid >= NBLK_U) ? 1 : 0;
  int wid2 = z ? (wid - NBLK_U) : wid;
  int split = wid2 >> 2;
  int bx = wid2 & 3;

  const unsigned short* Qhi = z ? QiH : QuH;
  const unsigned short* Qlo = z ? QiL : QuL;
  const unsigned short* Ehi = z ? EiHp : EuHp;
  const unsigned short* Elo = z ? EiLp : EuLp;
  const float* M0arr = z ? M0i : M0u;
  float* part_s = z ? psI : psU;
  int n_rows = z ? N_I : N_U;

  int tid = threadIdx.x;
  int wave = tid >> 6, lane = tid & 63;
  int l15 = lane & 15, quad = lane >> 4;
  int qbase = (bx * 4 + wave) * 128;
  int row0 = split * RSP;
  int row_end = min(row0 + RSP, n_rows);
  int rows = row_end - row0; if (rows < 0) rows = 0;
  int total = (rows + 15) >> 4;
  int ntail = rows & 15;

  float ss[8][4];
#pragma unroll
  for (int t = 0; t < 8; t++)
#pragma unroll
    for (int g = 0; g < 4; g++) ss[t][g] = 0.f;

  if (total > 0) {
    short8 ah[8][2], al[8][2];
#pragma unroll
    for (int t = 0; t < 8; t++)
#pragma unroll
      for (int c = 0; c < 2; c++) {
        size_t idx = (size_t)(qbase + t * 16 + l15) * 64 + c * 32 + quad * 8;
        ah[t][c] = *(const short8*)(Qhi + idx);
        al[t][c] = *(const short8*)(Qlo + idx);
      }

    f32x4 cinit[8];
#pragma unroll
    for (int t = 0; t < 8; t++)
#pragma unroll
      for (int g = 0; g < 4; g++)
        cinit[t][g] = -M0arr[qbase + t * 16 + quad * 4 + g];

    const unsigned short* ph = Ehi + (size_t)(row0 + l15) * 64 + quad * 8;
    const unsigned short* pl = Elo + (size_t)(row0 + l15) * 64 + quad * 8;

    short8 cb0 = *(const short8*)(ph);
    short8 cb1 = *(const short8*)(ph + 32);
    short8 cb2 = *(const short8*)(pl);
    short8 cb3 = *(const short8*)(pl + 32);
    ph += 1024; pl += 1024;

    for (int it = 0; it < total - 1; it++) {
      short8 nb0 = *(const short8*)(ph);
      short8 nb1 = *(const short8*)(ph + 32);
      short8 nb2 = *(const short8*)(pl);
      short8 nb3 = *(const short8*)(pl + 32);
      ph += 1024; pl += 1024;
#pragma unroll
      for (int t = 0; t < 8; t++) {
        f32x4 acc = cinit[t];
        acc = __builtin_amdgcn_mfma_f32_16x16x32_bf16(ah[t][0], cb0, acc, 0, 0, 0);
        acc = __builtin_amdgcn_mfma_f32_16x16x32_bf16(ah[t][1], cb1, acc, 0, 0, 0);
        acc = __builtin_amdgcn_mfma_f32_16x16x32_bf16(al[t][0], cb0, acc, 0, 0, 0);
        acc = __builtin_amdgcn_mfma_f32_16x16x32_bf16(al[t][1], cb1, acc, 0, 0, 0);
        acc = __builtin_amdgcn_mfma_f32_16x16x32_bf16(ah[t][0], cb2, acc, 0, 0, 0);
        acc = __builtin_amdgcn_mfma_f32_16x16x32_bf16(ah[t][1], cb3, acc, 0, 0, 0);
#pragma unroll
        for (int g = 0; g < 4; g++)
          ss[t][g] += exp2f(acc[g]);
      }
      cb0 = nb0; cb1 = nb1; cb2 = nb2; cb3 = nb3;
    }
    {
      bool valid = (ntail == 0) || (l15 < ntail);
#pragma unroll
      for (int t = 0; t < 8; t++) {
        f32x4 acc = cinit[t];
        acc = __builtin_amdgcn_mfma_f32_16x16x32_bf16(ah[t][0], cb0, acc, 0, 0, 0);
        acc = __builtin_amdgcn_mfma_f32_16x16x32_bf16(ah[t][1], cb1, acc, 0, 0, 0);
        acc = __builtin_amdgcn_mfma_f32_16x16x32_bf16(al[t][0], cb0, acc, 0, 0, 0);
        acc = __builtin_amdgcn_mfma_f32_16x16x32_bf16(al[t][1], cb1, acc, 0, 0, 0);
        acc = __builtin_amdgcn_mfma_f32_16x16x32_bf16(ah[t][0], cb2, acc, 0, 0, 0);
        acc = __builtin_amdgcn_mfma_f32_16x16x32_bf16(ah[t][1], cb3, acc, 0, 0, 0);
#pragma unroll
        for (int g = 0; g < 4; g++) {
          float e = exp2f(acc[g]);
          ss[t][g] += valid ? e : 0.f;
        }
      }
    }
  }

#pragma unroll
  for (int off = 1; off < 16; off <<= 1) {
#pragma unroll
    for (int t = 0; t < 8; t++)
#pragma unroll
      for (int g = 0; g < 4; g++)
        ss[t][g] += __shfl_xor(ss[t][g], off, 64);
  }

  if (l15 == 0) {
#pragma unroll
    for (int t = 0; t < 8; t++)
#pragma unroll
      for (int g = 0; g < 4; g++) {
        int q = qbase + t * 16 + quad * 4 + g;
        part_s[(size_t)split * B + q] = ss[t][g];
      }
  }
}

// ---------------- per-sample losses + fused finalize (8-block ticket, uncontended) ----------------
__global__ void k_small(const float* __restrict__ sEu, const float* __restrict__ sEi,
                        const float* __restrict__ sGu, const float* __restrict__ sGi,
                        const int* __restrict__ uids, const int* __restrict__ iids,
                        const int* __restrict__ pos, const int* __restrict__ neg,
                        const float* __restrict__ psU, const float* __restrict__ psI,
                        const float* __restrict__ M0u, const float* __restrict__ M0i,
                        float* acc, float* __restrict__ out) {
  int b = blockIdx.x * 256 + threadIdx.x;
  float du = 0.f, di = 0.f, nu = 0.f, ni = 0.f, bpr = 0.f;
  if (b < B) {
    float su = 0.f, si = 0.f;
    for (int s2 = 0; s2 < NSP_U; s2++) su += psU[(size_t)s2 * B + b];
    for (int s2 = 0; s2 < NSP_I; s2++) si += psI[(size_t)s2 * B + b];
    float lseu = M0u[b] * LN2F + logf(su);
    float lsei = M0i[b] * LN2F + logf(si);
    nu = fmaxf(lseu, LOG_EPS) + log1pf(expf(-fabsf(lseu - LOG_EPS)));
    ni = fmaxf(lsei, LOG_EPS) + log1pf(expf(-fabsf(lsei - LOG_EPS)));

    int u = uids[b], it = iids[b], p = pos[b], ng = neg[b];
    const float4* gu = (const float4*)(sGu + (size_t)u * D);
    const float4* eu = (const float4*)(sEu + (size_t)u * D);
    const float4* gi = (const float4*)(sGi + (size_t)it * D);
    const float4* ei = (const float4*)(sEi + (size_t)it * D);
    const float4* ep = (const float4*)(sEi + (size_t)p * D);
    const float4* en = (const float4*)(sEi + (size_t)ng * D);
    float diff = 0.f;
#pragma unroll
    for (int k = 0; k < 16; k++) {
      float4 a = gu[k], b4 = eu[k];
      du += a.x * b4.x + a.y * b4.y + a.z * b4.z + a.w * b4.w;
      float4 c = gi[k], d4 = ei[k];
      di += c.x * d4.x + c.y * d4.y + c.z * d4.z + c.w * d4.w;
      float4 e = ep[k], f = en[k];
      diff += b4.x * (e.x - f.x) + b4.y * (e.y - f.y) + b4.z * (e.z - f.z) + b4.w * (e.w - f.w);
    }
    bpr = (diff > 0.f) ? log1pf(expf(-diff)) : (-diff + log1pf(expf(diff)));
  }
  du = wred(du); di = wred(di); nu = wred(nu); ni = wred(ni); bpr = wred(bpr);
  if ((threadIdx.x & 63) == 0) {
    unsafeAtomicAdd(acc + 0, du);
    unsafeAtomicAdd(acc + 1, di);
    unsafeAtomicAdd(acc + 2, nu);
    unsafeAtomicAdd(acc + 3, ni);
    unsafeAtomicAdd(acc + 4, bpr);
  }
  __syncthreads();
  if (threadIdx.x == 0) {
    __threadfence();
    int ticket = atomicAdd((int*)(acc + 16), 1);
    if (ticket == (int)gridDim.x - 1) {
      __threadfence();
      float a0 = unsafeAtomicAdd(acc + 0, 0.f);
      float a1 = unsafeAtomicAdd(acc + 1, 0.f);
      float a2 = unsafeAtomicAdd(acc + 2, 0.f);
      float a3 = unsafeAtomicAdd(acc + 3, 0.f);
      float a4 = unsafeAtomicAdd(acc + 4, 0.f);
      float a5 = unsafeAtomicAdd(acc + 5, 0.f);
      float pos_score = (a0 + a1) * (INV_TEMP / (float)B);
      float neg_score = (a2 + a3) / (float)B;
      float loss_s = neg_score - pos_score;
      float loss_r = a4 / (float)B;
      float reg = LAMBDA2 * a5;
      out[0] = loss_r + LAMBDA1 * loss_s + reg;
      out[1] = loss_r;
      out[2] = LAMBDA1 * loss_s;
    }
  }
}

extern "C" void kernel_launch(void* const* d_in, const int* in_sizes, int n_in,
                              void* d_out, int out_size, void* d_ws, size_t ws_size,
                              hipStream_t stream) {
  const float* Eu0  = (const float*)d_in[0];
  const float* Ei0  = (const float*)d_in[1];
  const float* vals = (const float*)d_in[2];
  const float* W    = (const float*)d_in[3];
  const float* al   = (const float*)d_in[4];
  const float* ar   = (const float*)d_in[5];
  const int* ii     = (const int*)d_in[7];
  const int* uids   = (const int*)d_in[10];
  const int* iids   = (const int*)d_in[11];
  const int* pos    = (const int*)d_in[12];
  const int* neg    = (const int*)d_in[13];
  float* out = (float*)d_out;

  char* base = (char*)d_ws;
  size_t off = 0;
  auto alloc = [&](size_t bytes) -> void* {
    void* p = base + off;
    off = (off + bytes + 255) & ~(size_t)255;
    return p;
  };
  float* fU_a = (float*)alloc((size_t)N_U * 128 * 4);
  float* fU_b = (float*)alloc((size_t)N_U * 128 * 4);
  float* fI_a = (float*)alloc((size_t)N_I * 128 * 4);
  float* fI_b = (float*)alloc((size_t)N_I * 128 * 4);
  unsigned short* gU_a = (unsigned short*)alloc((size_t)N_U * 128 * 2);
  unsigned short* gU_b = (unsigned short*)alloc((size_t)N_U * 128 * 2);
  unsigned short* gI_a = (unsigned short*)alloc((size_t)N_I * 128 * 2);
  unsigned short* gI_b = (unsigned short*)alloc((size_t)N_I * 128 * 2);
  float* sEu  = (float*)alloc((size_t)N_U * D * 4);
  float* sEi  = (float*)alloc((size_t)N_I * D * 4);
  float* sGu  = (float*)alloc((size_t)N_U * D * 4);
  float* sGi  = (float*)alloc((size_t)N_I * D * 4);
  float* el   = (float*)alloc((size_t)N_TOT * 4 * 4);
  float* er   = (float*)alloc((size_t)N_TOT * 4 * 4);
  float* psU  = (float*)alloc((size_t)B * NSP_U * 4);
  float* psI  = (float*)alloc((size_t)B * NSP_I * 4);
  float* M0u  = (float*)alloc((size_t)B * 4);
  float* M0i  = (float*)alloc((size_t)B * 4);
  float* normU= (float*)alloc((size_t)N_U * 4);
  float* normI= (float*)alloc((size_t)N_I * 4);
  float* acc  = (float*)alloc(32 * 4);
  float* regp = (float*)alloc((size_t)NREGP * 4);
  int* deg    = (int*)alloc((size_t)N_I * 4);
  int* cursor = (int*)alloc((size_t)N_I * 4);
  int* rowptr = (int*)alloc((size_t)(N_I + 1) * 4);
  int* u_srt  = (int*)alloc((size_t)NNZ * 4);
  float* v_srt= (float*)alloc((size_t)NNZ * 4);
  unsigned short* EuH = (unsigned short*)alloc((size_t)PAD_U * 64 * 2);
  unsigned short* EuL = (unsigned short*)alloc((size_t)PAD_U * 64 * 2);
  unsigned short* EiH = (unsigned short*)alloc((size_t)PAD_I * 64 * 2);
  unsigned short* EiL = (unsigned short*)alloc((size_t)PAD_I * 64 * 2);
  unsigned short* QuH = (unsigned short*)alloc((size_t)B * 64 * 2);
  unsigned short* QuL = (unsigned short*)alloc((size_t)B * 64 * 2);
  unsigned short* QiH = (unsigned short*)alloc((size_t)B * 64 * 2);
  unsigned short* QiL = (unsigned short*)alloc((size_t)B * 64 * 2);

  k_init<<<NREGP, 256, 0, stream>>>(Eu0, Ei0, fU_a, fI_a, gU_a, gI_a,
                                    deg, acc, regp);
  k_deg<<<(NNZ + 255) / 256, 256, 0, stream>>>(ii, deg);
  k_scan<<<1, 1024, 0, stream>>>(deg, rowptr, cursor);
  k_fill<<<(NNZ + 255) / 256, 256, 0, stream>>>(ii, vals, cursor, u_srt, v_srt);

  float* cu = fU_a; float* ci = fI_a;
  float* nu = fU_b; float* ni = fI_b;
  unsigned short* gcu = gU_a; unsigned short* gci = gI_a;
  unsigned short* gnu = gU_b; unsigned short* gni = gI_b;
  for (int l = 0; l < 2; ++l) {
    float* elmx = acc + 8 + 4 * l;
    bool last = (l == 1);
    k_feat<<<(N_TOT + 15) / 16, 256, 0, stream>>>(cu, ci, gcu, gci, W, al, ar, el, er);
    k_elmax<<<64, 256, 0, stream>>>(el, elmx);
    k_layer<<<(N_TOT * D) / 256, 256, 0, stream>>>(
        cu, ci, gcu, gci, el, er, vals, ii, rowptr, u_srt, v_srt, elmx,
        Eu0, Ei0,
        nu, ni, gnu, gni, sEu, sEi, sGu, sGi,
        last ? EuH : nullptr, last ? EuL : nullptr,
        last ? EiH : nullptr, last ? EiL : nullptr,
        normU, normI);
    float* t1 = cu; cu = nu; nu = t1;
    float* t2 = ci; ci = ni; ni = t2;
    unsigned short* t3 = gcu; gcu = gnu; gnu = t3;
    unsigned short* t4 = gci; gci = gni; gni = t4;
  }

  k_normreg<<<128, 256, 0, stream>>>(normU, normI, regp, acc);
  k_cvt_q<<<(2 * B) / 4, 256, 0, stream>>>(sGu, sGi, uids, iids, QuH, QuL, QiH, QiL, acc, M0u, M0i);
  k_lse_mfma<<<NBLK, 256, 0, stream>>>(QuH, QuL, EuH, EuL,
                                       QiH, QiL, EiH, EiL,
                                       M0u, M0i, psU, psI);
  k_small<<<B / 256, 256, 0, stream>>>(sEu, sEi, sGu, sGi, uids, iids, pos, neg,
                                       psU, psI, M0u, M0i, acc, out);
}

// Round 17
// 384.034 us; speedup vs baseline: 1.0304x; 1.0304x over previous
//
#include <hip/hip_runtime.h>
#include <math.h>

#define N_U 30000
#define N_I 15000
#define N_TOT 45000
#define D 64
#define NNZ 480000
#define B 2048
#define INV_TEMP 5.0f
#define LOG_EPS -18.420680743952367f
#define NEG_SLOPE 0.2f
#define LAMBDA1 0.2f
#define LAMBDA2 1e-7f

// MFMA-lse config (r17): equal-work splits AND exactly 512 blocks (=2/CU, single residency
// wave). r16's 516 blocks overflowed the 512 capacity -> 4 stragglers ran a whole second
// pass (~22 iters) nearly solo: lse 48.5->61us. Now 4*(85+43)=512, RSP_U=353 / RSP_I=349
// -> every block 22-23 iters, all co-resident from t=0.
#define NSP_U 85
#define NSP_I 43
#define RSP_U 353
#define RSP_I 349
#define NBLK_U (4 * NSP_U)          // 340
#define NBLK (4 * (NSP_U + NSP_I))  // 512
#define PAD_U 30016
#define PAD_I 15040
#define SCALE_LOG2 7.2134752044448170f
#define LN2F 0.6931471805599453f
#define NREGP 2813  // k_init grid size = (N_TOT*16+255)/256

typedef __attribute__((ext_vector_type(8))) short short8;
typedef __attribute__((ext_vector_type(4))) float f32x4;

__device__ inline float wred(float v) {
#pragma unroll
  for (int o = 32; o > 0; o >>= 1) v += __shfl_down(v, o, 64);
  return v;
}

__device__ inline float leaky(float v) { return (v >= 0.f) ? v : NEG_SLOPE * v; }

__device__ inline void atomMaxF(float* a, float v) {
  if (v >= 0.f) atomicMax((int*)a, __float_as_int(v));
  else atomicMin((unsigned int*)a, __float_as_uint(v));
}

__device__ inline unsigned short f2bf(float x) {
  unsigned u = __float_as_uint(x);
  unsigned r = u + 0x7FFFu + ((u >> 16) & 1u);
  return (unsigned short)(r >> 16);
}
__device__ inline float bf2f(unsigned short h) {
  return __uint_as_float(((unsigned)h) << 16);
}

// ---------------- init: float4-vectorized; interleaved bf16 mirror; NO sE/sG writes (both
// deferred to last layer, bit-exact); fused per-block L2-reg partial sum ----------------
__global__ void k_init(const float* __restrict__ Eu0, const float* __restrict__ Ei0,
                       float* fU, float* fI,
                       unsigned short* gU, unsigned short* gI,
                       int* deg, float* acc,
                       float* __restrict__ regp) {
  __shared__ float red[4];
  int t = blockIdx.x * 256 + threadIdx.x;  // t in [0, N_TOT*16)
  if (t < 20) acc[t] = (t >= 8 && t < 16) ? -INFINITY : 0.f;
  if (t < N_I) deg[t] = 0;
  int n = t >> 4, q = t & 15;
  float s = 0.f;
  if (n < N_U) {
    float4 v = ((const float4*)Eu0)[t];
    ((float4*)(fU + (size_t)n * 128))[q] = v;
    uint4 gv = {(unsigned)f2bf(v.x), (unsigned)f2bf(v.y), (unsigned)f2bf(v.z), (unsigned)f2bf(v.w)};
    ((uint4*)(gU + (size_t)n * 128))[q] = gv;
    s = v.x * v.x + v.y * v.y + v.z * v.z + v.w * v.w;
  } else if (n < N_TOT) {
    int j = t - N_U * 16;
    int ni = n - N_U;
    float4 v = ((const float4*)Ei0)[j];
    ((float4*)(fI + (size_t)ni * 128))[q] = v;
    uint4 gv = {(unsigned)f2bf(v.x), (unsigned)f2bf(v.y), (unsigned)f2bf(v.z), (unsigned)f2bf(v.w)};
    ((uint4*)(gI + (size_t)ni * 128))[q] = gv;
    s = v.x * v.x + v.y * v.y + v.z * v.z + v.w * v.w;
  }
  s = wred(s);
  int lane = threadIdx.x & 63, wv = threadIdx.x >> 6;
  if (lane == 0) red[wv] = s;
  __syncthreads();
  if (threadIdx.x == 0)
    regp[blockIdx.x] = red[0] + red[1] + red[2] + red[3];
}

// ---------------- CSR build over item side ----------------
__global__ void k_deg(const int* __restrict__ ii, int* deg) {
  int e = blockIdx.x * 256 + threadIdx.x;
  if (e < NNZ) atomicAdd(&deg[ii[e]], 1);
}

// shuffle-based scan: 2 barriers, deg cached in registers (bit-exact int ops)
__global__ void k_scan(const int* __restrict__ deg, int* rowptr, int* cursor) {
  __shared__ int wtot[16], woff[16];
  const int CHUNK = 15;
  int tid = threadIdx.x, lane = tid & 63, wv = tid >> 6;
  int base = tid * CHUNK;
  int dv[CHUNK];
  int s = 0;
#pragma unroll
  for (int k = 0; k < CHUNK; k++) {
    int idx = base + k;
    dv[k] = (idx < N_I) ? deg[idx] : 0;
    s += dv[k];
  }
  int v = s;
#pragma unroll
  for (int o = 1; o < 64; o <<= 1) {
    int x = __shfl_up(v, o, 64);
    if (lane >= o) v += x;
  }
  if (lane == 63) wtot[wv] = v;
  __syncthreads();
  if (tid < 16) {
    int w = wtot[tid];
    int iv = w;
#pragma unroll
    for (int o = 1; o < 16; o <<= 1) {
      int x = __shfl_up(iv, o, 16);
      if (tid >= o) iv += x;
    }
    woff[tid] = iv - w;
  }
  __syncthreads();
  int excl = (v - s) + woff[wv];
#pragma unroll
  for (int k = 0; k < CHUNK; k++) {
    int idx = base + k;
    if (idx < N_I) {
      rowptr[idx] = excl;
      cursor[idx] = excl;
      excl += dv[k];
    }
  }
  if (tid == 1023) rowptr[N_I] = excl;
}

__global__ void k_fill(const int* __restrict__ ii, const float* __restrict__ vals,
                       int* cursor, int* u_srt, float* v_srt) {
  int e = blockIdx.x * 256 + threadIdx.x;
  if (e < NNZ) {
    int pos = atomicAdd(&cursor[ii[e]], 1);
    u_srt[pos] = e >> 4;
    v_srt[pos] = vals[e];
  }
}

// ---------------- GAT: feat = E @ W into fused[64:128] (fp32) + interleaved bf16 mirror, el/er ----------------
__global__ void k_feat(float* __restrict__ fU, float* __restrict__ fI,
                       unsigned short* __restrict__ gU, unsigned short* __restrict__ gI,
                       const float* __restrict__ W, const float* __restrict__ al,
                       const float* __restrict__ ar,
                       float* __restrict__ el, float* __restrict__ er) {
  __shared__ float Ws[64 * 64];
  __shared__ float hs[16][64];
  int tid = threadIdx.x;
  for (int t = tid; t < 1024; t += 256) ((float4*)Ws)[t] = ((const float4*)W)[t];
  int g = tid >> 6, c = tid & 63;
  int n0 = blockIdx.x * 16 + g * 4;
  float* rows[4];
  unsigned short* grows[4];
#pragma unroll
  for (int j = 0; j < 4; j++) {
    int node = n0 + j;
    rows[j] = nullptr; grows[j] = nullptr;
    if (node < N_TOT) {
      if (node < N_U) {
        rows[j] = fU + (size_t)node * 128;
        grows[j] = gU + (size_t)node * 128;
      } else {
        rows[j] = fI + (size_t)(node - N_U) * 128;
        grows[j] = gI + (size_t)(node - N_U) * 128;
      }
      hs[g * 4 + j][c] = rows[j][c];
    }
  }
  __syncthreads();
  float a0 = 0.f, a1 = 0.f, a2 = 0.f, a3 = 0.f;
#pragma unroll 8
  for (int k = 0; k < 64; ++k) {
    float w = Ws[k * 64 + c];
    a0 = fmaf(hs[g * 4 + 0][k], w, a0);
    a1 = fmaf(hs[g * 4 + 1][k], w, a1);
    a2 = fmaf(hs[g * 4 + 2][k], w, a2);
    a3 = fmaf(hs[g * 4 + 3][k], w, a3);
  }
  float accs[4] = {a0, a1, a2, a3};
  float alc = al[c], arc = ar[c];
#pragma unroll
  for (int j = 0; j < 4; j++) {
    int node = n0 + j;
    if (node >= N_TOT) continue;
    rows[j][64 + c] = accs[j];
    grows[j][2 * c + 1] = f2bf(accs[j]);
    float pl = accs[j] * alc;
    float pr = accs[j] * arc;
#pragma unroll
    for (int o = 8; o >= 1; o >>= 1) {
      pl += __shfl_down(pl, o, 16);
      pr += __shfl_down(pr, o, 16);
    }
    if ((c & 15) == 0) {
      el[node * 4 + (c >> 4)] = pl;
      er[node * 4 + (c >> 4)] = pr;
    }
  }
}

// ---------------- per-head global max of el (separate kernel: few atomics; r7 lesson) ----------------
__global__ void k_elmax(const float* __restrict__ el, float* __restrict__ dst) {
  __shared__ float red[4][4];
  int tid = threadIdx.x;
  int lane = tid & 63, wv = tid >> 6;
  float mx = -INFINITY;
  for (int t = blockIdx.x * 256 + tid; t < N_TOT * 4; t += 64 * 256)
    mx = fmaxf(mx, el[t]);
#pragma unroll
  for (int o = 4; o < 64; o <<= 1) mx = fmaxf(mx, __shfl_xor(mx, o, 64));
  if (lane < 4) red[wv][lane] = mx;
  __syncthreads();
  if (tid < 4) {
    float m2 = fmaxf(fmaxf(red[0][tid], red[1][tid]), fmaxf(red[2][tid], red[3][tid]));
    atomMaxF(dst + tid, m2);
  }
}

// ---------------- fused graph layer ----------------
// r10: exp-dedup via shfl + interleaved-mirror gathers.
// r13: deferred sE — last layer computes s_final=(E0+selfrow)+e_new (bit-exact).
// r14: deferred sG — layer1 stores g1; last layer sG=(E0+g1)+g2; dead-store elim on last layer.
__global__ void k_layer(const float* __restrict__ fU_cur, const float* __restrict__ fI_cur,
                        const unsigned short* __restrict__ gU_cur,
                        const unsigned short* __restrict__ gI_cur,
                        const float* __restrict__ el, const float* __restrict__ er,
                        const float* __restrict__ vals, const int* __restrict__ ii,
                        const int* __restrict__ rowptr, const int* __restrict__ u_srt,
                        const float* __restrict__ v_srt,
                        const float* __restrict__ elmx,
                        const float* __restrict__ E0u, const float* __restrict__ E0i,
                        float* __restrict__ fU_nxt, float* __restrict__ fI_nxt,
                        unsigned short* __restrict__ gU_nxt, unsigned short* __restrict__ gI_nxt,
                        float* __restrict__ sEu, float* __restrict__ sEi,
                        float* __restrict__ sGu, float* __restrict__ sGi,
                        unsigned short* __restrict__ EuH, unsigned short* __restrict__ EuL,
                        unsigned short* __restrict__ EiH, unsigned short* __restrict__ EiL,
                        float* __restrict__ normU, float* __restrict__ normI) {
  int t = blockIdx.x * 256 + threadIdx.x;
  int node = t >> 6, c = t & 63;
  if (node >= N_TOT) return;
  int h = c >> 4;
  int k2 = c & 15;

  if (node < N_U) {
    int u = node;
    float eru = er[u * 4 + h];
    float m = leaky(elmx[h] + eru);
    const float* selfrow = fU_cur + (size_t)u * 128;
    float aself = __expf(leaky(el[u * 4 + h] + eru) - m);

    int idx[16]; float vv[16];
#pragma unroll
    for (int k = 0; k < 16; k++) { idx[k] = ii[u * 16 + k]; vv[k] = vals[u * 16 + k]; }

    float ev = __expf(leaky(el[(ii[u * 16 + k2] + N_U) * 4 + h] + eru) - m);
    float av[16];
#pragma unroll
    for (int k = 0; k < 16; k++)
      av[k] = __shfl(ev, (c & 48) | k, 64);

    float den = aself;
#pragma unroll
    for (int k = 0; k < 16; k++) den += av[k];

    float o0 = aself * selfrow[64 + c], o1 = 0.f;
    float z0 = 0.f, z1 = 0.f;
#pragma unroll
    for (int k = 0; k < 16; k += 2) {
      unsigned wA = *(const unsigned*)(gI_cur + (size_t)idx[k] * 128 + 2 * c);
      unsigned wB = *(const unsigned*)(gI_cur + (size_t)idx[k + 1] * 128 + 2 * c);
      float eA = __uint_as_float(wA << 16), fA = __uint_as_float(wA & 0xFFFF0000u);
      float eB = __uint_as_float(wB << 16), fB = __uint_as_float(wB & 0xFFFF0000u);
      z0 = fmaf(vv[k], eA, z0);
      z1 = fmaf(vv[k + 1], eB, z1);
      o0 = fmaf(av[k], fA, o0);
      o1 = fmaf(av[k + 1], fB, o1);
    }
    float o = (o0 + o1) / den;
    float g = (o > 0.f) ? o : expm1f(o);
    float e_new = selfrow[c] + z0 + z1;
    size_t off = (size_t)u * D + c;
    if (EuH) {
      float e0v = E0u[off];
      float s_final = (e0v + selfrow[c]) + e_new;
      sEu[off] = s_final;
      sGu[off] = (e0v + sGu[off]) + g;
      unsigned short hi = f2bf(s_final);
      EuH[off] = hi;
      EuL[off] = f2bf(s_final - bf2f(hi));
      float n2 = wred(s_final * s_final);
      if (c == 0) normU[u] = n2;
    } else {
      fU_nxt[(size_t)u * 128 + c] = e_new;
      gU_nxt[(size_t)u * 128 + 2 * c] = f2bf(e_new);
      sGu[off] = g;
    }
  } else {
    int i = node - N_U;
    float eri = er[node * 4 + h];
    float m = leaky(elmx[h] + eri);
    const float* selfrow = fI_cur + (size_t)i * 128;
    float aself = __expf(leaky(el[node * 4 + h] + eri) - m);
    float den0 = aself, den1 = 0.f;
    float o0 = aself * selfrow[64 + c], o1 = 0.f;
    float z0 = 0.f, z1 = 0.f;
    int r0 = rowptr[i], r1 = rowptr[i + 1];
    for (int rb = r0; rb < r1; rb += 16) {
      int cnt = min(16, r1 - rb);
      int rr = rb + (k2 < cnt ? k2 : cnt - 1);
      float ev = __expf(leaky(el[u_srt[rr] * 4 + h] + eri) - m);
      int k = 0;
      for (; k + 3 < cnt; k += 4) {
        int u0 = u_srt[rb + k], u1 = u_srt[rb + k + 1], u2 = u_srt[rb + k + 2], u3 = u_srt[rb + k + 3];
        float v0 = v_srt[rb + k], v1 = v_srt[rb + k + 1], v2 = v_srt[rb + k + 2], v3 = v_srt[rb + k + 3];
        float a0 = __shfl(ev, (c & 48) | k, 64);
        float a1 = __shfl(ev, (c & 48) | (k + 1), 64);
        float a2 = __shfl(ev, (c & 48) | (k + 2), 64);
        float a3 = __shfl(ev, (c & 48) | (k + 3), 64);
        unsigned w0 = *(const unsigned*)(gU_cur + (size_t)u0 * 128 + 2 * c);
        unsigned w1 = *(const unsigned*)(gU_cur + (size_t)u1 * 128 + 2 * c);
        unsigned w2 = *(const unsigned*)(gU_cur + (size_t)u2 * 128 + 2 * c);
        unsigned w3 = *(const unsigned*)(gU_cur + (size_t)u3 * 128 + 2 * c);
        float e0 = __uint_as_float(w0 << 16), f0 = __uint_as_float(w0 & 0xFFFF0000u);
        float e1 = __uint_as_float(w1 << 16), f1 = __uint_as_float(w1 & 0xFFFF0000u);
        float e2 = __uint_as_float(w2 << 16), f2 = __uint_as_float(w2 & 0xFFFF0000u);
        float e3 = __uint_as_float(w3 << 16), f3 = __uint_as_float(w3 & 0xFFFF0000u);
        z0 = fmaf(v0, e0, z0); z1 = fmaf(v1, e1, z1);
        z0 = fmaf(v2, e2, z0); z1 = fmaf(v3, e3, z1);
        den0 += a0 + a2; den1 += a1 + a3;
        o0 = fmaf(a0, f0, o0); o1 = fmaf(a1, f1, o1);
        o0 = fmaf(a2, f2, o0); o1 = fmaf(a3, f3, o1);
      }
      for (; k < cnt; k++) {
        int u0 = u_srt[rb + k];
        float v0 = v_srt[rb + k];
        float a0 = __shfl(ev, (c & 48) | k, 64);
        unsigned w0 = *(const unsigned*)(gU_cur + (size_t)u0 * 128 + 2 * c);
        float e0 = __uint_as_float(w0 << 16), f0 = __uint_as_float(w0 & 0xFFFF0000u);
        z0 = fmaf(v0, e0, z0);
        den0 += a0;
        o0 = fmaf(a0, f0, o0);
      }
    }
    float o = (o0 + o1) / (den0 + den1);
    float g = (o > 0.f) ? o : expm1f(o);
    float e_new = selfrow[c] + z0 + z1;
    size_t off = (size_t)i * D + c;
    if (EiH) {
      float e0v = E0i[off];
      float s_final = (e0v + selfrow[c]) + e_new;
      sEi[off] = s_final;
      sGi[off] = (e0v + sGi[off]) + g;
      unsigned short hi = f2bf(s_final);
      EiH[off] = hi;
      EiL[off] = f2bf(s_final - bf2f(hi));
      float n2 = wred(s_final * s_final);
      if (c == 0) normI[i] = n2;
    } else {
      fI_nxt[(size_t)i * 128 + c] = e_new;
      gI_nxt[(size_t)i * 128 + 2 * c] = f2bf(e_new);
      sGi[off] = g;
    }
  }
}

// ---------------- max row-norm reduce + L2 reg reduce (reads per-block partials from k_init) ----------------
__global__ void k_normreg(const float* __restrict__ nU, const float* __restrict__ nI,
                          const float* __restrict__ regp,
                          float* __restrict__ acc) {
  __shared__ float red[4][3];
  int tid = threadIdx.x;
  int lane = tid & 63, wv = tid >> 6;
  float mu = 0.f, mi = 0.f, s = 0.f;
  for (int t = blockIdx.x * 256 + tid; t < N_U; t += 128 * 256) mu = fmaxf(mu, nU[t]);
  for (int t = blockIdx.x * 256 + tid; t < N_I; t += 128 * 256) mi = fmaxf(mi, nI[t]);
  for (int t = blockIdx.x * 256 + tid; t < NREGP; t += 128 * 256) s += regp[t];
#pragma unroll
  for (int o = 32; o > 0; o >>= 1) {
    mu = fmaxf(mu, __shfl_down(mu, o, 64));
    mi = fmaxf(mi, __shfl_down(mi, o, 64));
    s += __shfl_down(s, o, 64);
  }
  if (lane == 0) { red[wv][0] = mu; red[wv][1] = mi; red[wv][2] = s; }
  __syncthreads();
  if (tid == 0) {
    float a = fmaxf(fmaxf(red[0][0], red[1][0]), fmaxf(red[2][0], red[3][0]));
    float b = fmaxf(fmaxf(red[0][1], red[1][1]), fmaxf(red[2][1], red[3][1]));
    float ssum = red[0][2] + red[1][2] + red[2][2] + red[3][2];
    atomMaxF(acc + 6, a);
    atomMaxF(acc + 7, b);
    unsafeAtomicAdd(acc + 5, ssum);
  }
}

// ---------------- gathered queries: pre-scaled split-bf16 + Cauchy-Schwarz offset M0 ----------------
__global__ void k_cvt_q(const float* __restrict__ sGu, const float* __restrict__ sGi,
                        const int* __restrict__ uids, const int* __restrict__ iids,
                        unsigned short* __restrict__ QuH, unsigned short* __restrict__ QuL,
                        unsigned short* __restrict__ QiH, unsigned short* __restrict__ QiL,
                        const float* __restrict__ acc,
                        float* __restrict__ M0u, float* __restrict__ M0i) {
  int lane = threadIdx.x & 63, wv = threadIdx.x >> 6;
  int row = blockIdx.x * 4 + wv;
  int side = row >> 11;
  int b = row & (B - 1);
  int id = side ? iids[b] : uids[b];
  float x = (side ? sGi : sGu)[(size_t)id * 64 + lane] * SCALE_LOG2;
  unsigned short hi = f2bf(x);
  unsigned short lo = f2bf(x - bf2f(hi));
  if (side) { QiH[(size_t)b * 64 + lane] = hi; QiL[(size_t)b * 64 + lane] = lo; }
  else      { QuH[(size_t)b * 64 + lane] = hi; QuL[(size_t)b * 64 + lane] = lo; }
  float n2 = wred(x * x);
  if (lane == 0) {
    float en2 = side ? acc[7] : acc[6];
    float M0 = sqrtf(n2) * sqrtf(en2) * 1.01f + 1.0f;
    (side ? M0i : M0u)[b] = M0;
  }
}

// ---------------- MFMA logsumexp: r2-exact inner loop; equal-work 512-block grid (r17) ----------------
// (256,2)+t=8+depth-1 proven r2-r6. 512 blocks = exactly 2/CU: U wid<340, I wid>=340;
// split=wid>>2, qb=wid&3 (consecutive blocks share a split).
__global__ __launch_bounds__(256, 2) void k_lse_mfma(
    const unsigned short* __restrict__ QuH, const unsigned short* __restrict__ QuL,
    const unsigned short* __restrict__ EuHp, const unsigned short* __restrict__ EuLp,
    const unsigned short* __restrict__ QiH, const unsigned short* __restrict__ QiL,
    const unsigned short* __restrict__ EiHp, const unsigned short* __restrict__ EiLp,
    const float* __restrict__ M0u, const float* __restrict__ M0i,
    float* __restrict__ psU, float* __restrict__ psI) {
  int wid = blockIdx.x;
  int z = (wid >= NBLK_U) ? 1 : 0;
  int wid2 = z ? (wid - NBLK_U) : wid;
  int split = wid2 >> 2;
  int bx = wid2 & 3;

  const unsigned short* Qhi = z ? QiH : QuH;
  const unsigned short* Qlo = z ? QiL : QuL;
  const unsigned short* Ehi = z ? EiHp : EuHp;
  const unsigned short* Elo = z ? EiLp : EuLp;
  const float* M0arr = z ? M0i : M0u;
  float* part_s = z ? psI : psU;
  int n_rows = z ? N_I : N_U;
  int rsp = z ? RSP_I : RSP_U;

  int tid = threadIdx.x;
  int wave = tid >> 6, lane = tid & 63;
  int l15 = lane & 15, quad = lane >> 4;
  int qbase = (bx * 4 + wave) * 128;
  int row0 = split * rsp;
  int row_end = min(row0 + rsp, n_rows);
  int rows = row_end - row0; if (rows < 0) rows = 0;
  int total = (rows + 15) >> 4;
  int ntail = rows & 15;

  float ss[8][4];
#pragma unroll
  for (int t = 0; t < 8; t++)
#pragma unroll
    for (int g = 0; g < 4; g++) ss[t][g] = 0.f;

  if (total > 0) {
    short8 ah[8][2], al[8][2];
#pragma unroll
    for (int t = 0; t < 8; t++)
#pragma unroll
      for (int c = 0; c < 2; c++) {
        size_t idx = (size_t)(qbase + t * 16 + l15) * 64 + c * 32 + quad * 8;
        ah[t][c] = *(const short8*)(Qhi + idx);
        al[t][c] = *(const short8*)(Qlo + idx);
      }

    f32x4 cinit[8];
#pragma unroll
    for (int t = 0; t < 8; t++)
#pragma unroll
      for (int g = 0; g < 4; g++)
        cinit[t][g] = -M0arr[qbase + t * 16 + quad * 4 + g];

    const unsigned short* ph = Ehi + (size_t)(row0 + l15) * 64 + quad * 8;
    const unsigned short* pl = Elo + (size_t)(row0 + l15) * 64 + quad * 8;

    short8 cb0 = *(const short8*)(ph);
    short8 cb1 = *(const short8*)(ph + 32);
    short8 cb2 = *(const short8*)(pl);
    short8 cb3 = *(const short8*)(pl + 32);
    ph += 1024; pl += 1024;

    for (int it = 0; it < total - 1; it++) {
      short8 nb0 = *(const short8*)(ph);
      short8 nb1 = *(const short8*)(ph + 32);
      short8 nb2 = *(const short8*)(pl);
      short8 nb3 = *(const short8*)(pl + 32);
      ph += 1024; pl += 1024;
#pragma unroll
      for (int t = 0; t < 8; t++) {
        f32x4 acc = cinit[t];
        acc = __builtin_amdgcn_mfma_f32_16x16x32_bf16(ah[t][0], cb0, acc, 0, 0, 0);
        acc = __builtin_amdgcn_mfma_f32_16x16x32_bf16(ah[t][1], cb1, acc, 0, 0, 0);
        acc = __builtin_amdgcn_mfma_f32_16x16x32_bf16(al[t][0], cb0, acc, 0, 0, 0);
        acc = __builtin_amdgcn_mfma_f32_16x16x32_bf16(al[t][1], cb1, acc, 0, 0, 0);
        acc = __builtin_amdgcn_mfma_f32_16x16x32_bf16(ah[t][0], cb2, acc, 0, 0, 0);
        acc = __builtin_amdgcn_mfma_f32_16x16x32_bf16(ah[t][1], cb3, acc, 0, 0, 0);
#pragma unroll
        for (int g = 0; g < 4; g++)
          ss[t][g] += exp2f(acc[g]);
      }
      cb0 = nb0; cb1 = nb1; cb2 = nb2; cb3 = nb3;
    }
    {
      bool valid = (ntail == 0) || (l15 < ntail);
#pragma unroll
      for (int t = 0; t < 8; t++) {
        f32x4 acc = cinit[t];
        acc = __builtin_amdgcn_mfma_f32_16x16x32_bf16(ah[t][0], cb0, acc, 0, 0, 0);
        acc = __builtin_amdgcn_mfma_f32_16x16x32_bf16(ah[t][1], cb1, acc, 0, 0, 0);
        acc = __builtin_amdgcn_mfma_f32_16x16x32_bf16(al[t][0], cb0, acc, 0, 0, 0);
        acc = __builtin_amdgcn_mfma_f32_16x16x32_bf16(al[t][1], cb1, acc, 0, 0, 0);
        acc = __builtin_amdgcn_mfma_f32_16x16x32_bf16(ah[t][0], cb2, acc, 0, 0, 0);
        acc = __builtin_amdgcn_mfma_f32_16x16x32_bf16(ah[t][1], cb3, acc, 0, 0, 0);
#pragma unroll
        for (int g = 0; g < 4; g++) {
          float e = exp2f(acc[g]);
          ss[t][g] += valid ? e : 0.f;
        }
      }
    }
  }

#pragma unroll
  for (int off = 1; off < 16; off <<= 1) {
#pragma unroll
    for (int t = 0; t < 8; t++)
#pragma unroll
      for (int g = 0; g < 4; g++)
        ss[t][g] += __shfl_xor(ss[t][g], off, 64);
  }

  if (l15 == 0) {
#pragma unroll
    for (int t = 0; t < 8; t++)
#pragma unroll
      for (int g = 0; g < 4; g++) {
        int q = qbase + t * 16 + quad * 4 + g;
        part_s[(size_t)split * B + q] = ss[t][g];
      }
  }
}

// ---------------- per-sample losses + fused finalize (8-block ticket, uncontended) ----------------
__global__ void k_small(const float* __restrict__ sEu, const float* __restrict__ sEi,
                        const float* __restrict__ sGu, const float* __restrict__ sGi,
                        const int* __restrict__ uids, const int* __restrict__ iids,
                        const int* __restrict__ pos, const int* __restrict__ neg,
                        const float* __restrict__ psU, const float* __restrict__ psI,
                        const float* __restrict__ M0u, const float* __restrict__ M0i,
                        float* acc, float* __restrict__ out) {
  int b = blockIdx.x * 256 + threadIdx.x;
  float du = 0.f, di = 0.f, nu = 0.f, ni = 0.f, bpr = 0.f;
  if (b < B) {
    float su = 0.f, si = 0.f;
    for (int s2 = 0; s2 < NSP_U; s2++) su += psU[(size_t)s2 * B + b];
    for (int s2 = 0; s2 < NSP_I; s2++) si += psI[(size_t)s2 * B + b];
    float lseu = M0u[b] * LN2F + logf(su);
    float lsei = M0i[b] * LN2F + logf(si);
    nu = fmaxf(lseu, LOG_EPS) + log1pf(expf(-fabsf(lseu - LOG_EPS)));
    ni = fmaxf(lsei, LOG_EPS) + log1pf(expf(-fabsf(lsei - LOG_EPS)));

    int u = uids[b], it = iids[b], p = pos[b], ng = neg[b];
    const float4* gu = (const float4*)(sGu + (size_t)u * D);
    const float4* eu = (const float4*)(sEu + (size_t)u * D);
    const float4* gi = (const float4*)(sGi + (size_t)it * D);
    const float4* ei = (const float4*)(sEi + (size_t)it * D);
    const float4* ep = (const float4*)(sEi + (size_t)p * D);
    const float4* en = (const float4*)(sEi + (size_t)ng * D);
    float diff = 0.f;
#pragma unroll
    for (int k = 0; k < 16; k++) {
      float4 a = gu[k], b4 = eu[k];
      du += a.x * b4.x + a.y * b4.y + a.z * b4.z + a.w * b4.w;
      float4 c = gi[k], d4 = ei[k];
      di += c.x * d4.x + c.y * d4.y + c.z * d4.z + c.w * d4.w;
      float4 e = ep[k], f = en[k];
      diff += b4.x * (e.x - f.x) + b4.y * (e.y - f.y) + b4.z * (e.z - f.z) + b4.w * (e.w - f.w);
    }
    bpr = (diff > 0.f) ? log1pf(expf(-diff)) : (-diff + log1pf(expf(diff)));
  }
  du = wred(du); di = wred(di); nu = wred(nu); ni = wred(ni); bpr = wred(bpr);
  if ((threadIdx.x & 63) == 0) {
    unsafeAtomicAdd(acc + 0, du);
    unsafeAtomicAdd(acc + 1, di);
    unsafeAtomicAdd(acc + 2, nu);
    unsafeAtomicAdd(acc + 3, ni);
    unsafeAtomicAdd(acc + 4, bpr);
  }
  __syncthreads();
  if (threadIdx.x == 0) {
    __threadfence();
    int ticket = atomicAdd((int*)(acc + 16), 1);
    if (ticket == (int)gridDim.x - 1) {
      __threadfence();
      float a0 = unsafeAtomicAdd(acc + 0, 0.f);
      float a1 = unsafeAtomicAdd(acc + 1, 0.f);
      float a2 = unsafeAtomicAdd(acc + 2, 0.f);
      float a3 = unsafeAtomicAdd(acc + 3, 0.f);
      float a4 = unsafeAtomicAdd(acc + 4, 0.f);
      float a5 = unsafeAtomicAdd(acc + 5, 0.f);
      float pos_score = (a0 + a1) * (INV_TEMP / (float)B);
      float neg_score = (a2 + a3) / (float)B;
      float loss_s = neg_score - pos_score;
      float loss_r = a4 / (float)B;
      float reg = LAMBDA2 * a5;
      out[0] = loss_r + LAMBDA1 * loss_s + reg;
      out[1] = loss_r;
      out[2] = LAMBDA1 * loss_s;
    }
  }
}

extern "C" void kernel_launch(void* const* d_in, const int* in_sizes, int n_in,
                              void* d_out, int out_size, void* d_ws, size_t ws_size,
                              hipStream_t stream) {
  const float* Eu0  = (const float*)d_in[0];
  const float* Ei0  = (const float*)d_in[1];
  const float* vals = (const float*)d_in[2];
  const float* W    = (const float*)d_in[3];
  const float* al   = (const float*)d_in[4];
  const float* ar   = (const float*)d_in[5];
  const int* ii     = (const int*)d_in[7];
  const int* uids   = (const int*)d_in[10];
  const int* iids   = (const int*)d_in[11];
  const int* pos    = (const int*)d_in[12];
  const int* neg    = (const int*)d_in[13];
  float* out = (float*)d_out;

  char* base = (char*)d_ws;
  size_t off = 0;
  auto alloc = [&](size_t bytes) -> void* {
    void* p = base + off;
    off = (off + bytes + 255) & ~(size_t)255;
    return p;
  };
  float* fU_a = (float*)alloc((size_t)N_U * 128 * 4);
  float* fU_b = (float*)alloc((size_t)N_U * 128 * 4);
  float* fI_a = (float*)alloc((size_t)N_I * 128 * 4);
  float* fI_b = (float*)alloc((size_t)N_I * 128 * 4);
  unsigned short* gU_a = (unsigned short*)alloc((size_t)N_U * 128 * 2);
  unsigned short* gU_b = (unsigned short*)alloc((size_t)N_U * 128 * 2);
  unsigned short* gI_a = (unsigned short*)alloc((size_t)N_I * 128 * 2);
  unsigned short* gI_b = (unsigned short*)alloc((size_t)N_I * 128 * 2);
  float* sEu  = (float*)alloc((size_t)N_U * D * 4);
  float* sEi  = (float*)alloc((size_t)N_I * D * 4);
  float* sGu  = (float*)alloc((size_t)N_U * D * 4);
  float* sGi  = (float*)alloc((size_t)N_I * D * 4);
  float* el   = (float*)alloc((size_t)N_TOT * 4 * 4);
  float* er   = (float*)alloc((size_t)N_TOT * 4 * 4);
  float* psU  = (float*)alloc((size_t)B * NSP_U * 4);
  float* psI  = (float*)alloc((size_t)B * NSP_I * 4);
  float* M0u  = (float*)alloc((size_t)B * 4);
  float* M0i  = (float*)alloc((size_t)B * 4);
  float* normU= (float*)alloc((size_t)N_U * 4);
  float* normI= (float*)alloc((size_t)N_I * 4);
  float* acc  = (float*)alloc(32 * 4);
  float* regp = (float*)alloc((size_t)NREGP * 4);
  int* deg    = (int*)alloc((size_t)N_I * 4);
  int* cursor = (int*)alloc((size_t)N_I * 4);
  int* rowptr = (int*)alloc((size_t)(N_I + 1) * 4);
  int* u_srt  = (int*)alloc((size_t)NNZ * 4);
  float* v_srt= (float*)alloc((size_t)NNZ * 4);
  unsigned short* EuH = (unsigned short*)alloc((size_t)PAD_U * 64 * 2);
  unsigned short* EuL = (unsigned short*)alloc((size_t)PAD_U * 64 * 2);
  unsigned short* EiH = (unsigned short*)alloc((size_t)PAD_I * 64 * 2);
  unsigned short* EiL = (unsigned short*)alloc((size_t)PAD_I * 64 * 2);
  unsigned short* QuH = (unsigned short*)alloc((size_t)B * 64 * 2);
  unsigned short* QuL = (unsigned short*)alloc((size_t)B * 64 * 2);
  unsigned short* QiH = (unsigned short*)alloc((size_t)B * 64 * 2);
  unsigned short* QiL = (unsigned short*)alloc((size_t)B * 64 * 2);

  k_init<<<NREGP, 256, 0, stream>>>(Eu0, Ei0, fU_a, fI_a, gU_a, gI_a,
                                    deg, acc, regp);
  k_deg<<<(NNZ + 255) / 256, 256, 0, stream>>>(ii, deg);
  k_scan<<<1, 1024, 0, stream>>>(deg, rowptr, cursor);
  k_fill<<<(NNZ + 255) / 256, 256, 0, stream>>>(ii, vals, cursor, u_srt, v_srt);

  float* cu = fU_a; float* ci = fI_a;
  float* nu = fU_b; float* ni = fI_b;
  unsigned short* gcu = gU_a; unsigned short* gci = gI_a;
  unsigned short* gnu = gU_b; unsigned short* gni = gI_b;
  for (int l = 0; l < 2; ++l) {
    float* elmx = acc + 8 + 4 * l;
    bool last = (l == 1);
    k_feat<<<(N_TOT + 15) / 16, 256, 0, stream>>>(cu, ci, gcu, gci, W, al, ar, el, er);
    k_elmax<<<64, 256, 0, stream>>>(el, elmx);
    k_layer<<<(N_TOT * D) / 256, 256, 0, stream>>>(
        cu, ci, gcu, gci, el, er, vals, ii, rowptr, u_srt, v_srt, elmx,
        Eu0, Ei0,
        nu, ni, gnu, gni, sEu, sEi, sGu, sGi,
        last ? EuH : nullptr, last ? EuL : nullptr,
        last ? EiH : nullptr, last ? EiL : nullptr,
        normU, normI);
    float* t1 = cu; cu = nu; nu = t1;
    float* t2 = ci; ci = ni; ni = t2;
    unsigned short* t3 = gcu; gcu = gnu; gnu = t3;
    unsigned short* t4 = gci; gci = gni; gni = t4;
  }

  k_normreg<<<128, 256, 0, stream>>>(normU, normI, regp, acc);
  k_cvt_q<<<(2 * B) / 4, 256, 0, stream>>>(sGu, sGi, uids, iids, QuH, QuL, QiH, QiL, acc, M0u, M0i);
  k_lse_mfma<<<NBLK, 256, 0, stream>>>(QuH, QuL, EuH, EuL,
                                       QiH, QiL, EiH, EiL,
                                       M0u, M0i, psU, psI);
  k_small<<<B / 256, 256, 0, stream>>>(sEu, sEi, sGu, sGi, uids, iids, pos, neg,
                                       psU, psI, M0u, M0i, acc, out);
}

// Round 20
// 375.618 us; speedup vs baseline: 1.0535x; 1.0224x over previous
//
#include <hip/hip_runtime.h>
#include <math.h>

#define N_U 30000
#define N_I 15000
#define N_TOT 45000
#define D 64
#define NNZ 480000
#define B 2048
#define INV_TEMP 5.0f
#define LOG_EPS -18.420680743952367f
#define NEG_SLOPE 0.2f
#define LAMBDA1 0.2f
#define LAMBDA2 1e-7f

// MFMA-lse config: NSP=64, dim3(4,64,2) — EMPIRICAL OPTIMUM (r15: 48.5us).
// Refuted alternatives: NSP=128 (r10: 57us), XCD swizzle (r5: +10), t=4 (r3: 75),
// bounds(256,3) (r4: spill), depth-2 (r6: spill), equal-work 516 (r16: 61 — capacity
// overflow stragglers), equal-work 512 (r17: 52.7 — balanced 2-block contention beats
// nothing; the U-solo tail runs at higher per-wave throughput than modeled).
#define NSP 64
#define RSP_U 469
#define RSP_I 235
#define PAD_U 30016
#define PAD_I 15040
#define SCALE_LOG2 7.2134752044448170f
#define LN2F 0.6931471805599453f
#define NREGP 2813  // k_init grid size = (N_TOT*16+255)/256

typedef __attribute__((ext_vector_type(8))) short short8;
typedef __attribute__((ext_vector_type(4))) float f32x4;

__device__ inline float wred(float v) {
#pragma unroll
  for (int o = 32; o > 0; o >>= 1) v += __shfl_down(v, o, 64);
  return v;
}

__device__ inline float leaky(float v) { return (v >= 0.f) ? v : NEG_SLOPE * v; }

__device__ inline void atomMaxF(float* a, float v) {
  if (v >= 0.f) atomicMax((int*)a, __float_as_int(v));
  else atomicMin((unsigned int*)a, __float_as_uint(v));
}

__device__ inline unsigned short f2bf(float x) {
  unsigned u = __float_as_uint(x);
  unsigned r = u + 0x7FFFu + ((u >> 16) & 1u);
  return (unsigned short)(r >> 16);
}
__device__ inline float bf2f(unsigned short h) {
  return __uint_as_float(((unsigned)h) << 16);
}

// ---------------- init: float4-vectorized; interleaved bf16 mirror; NO sE/sG writes (both
// deferred to last layer, bit-exact); fused per-block L2-reg partial sum ----------------
__global__ void k_init(const float* __restrict__ Eu0, const float* __restrict__ Ei0,
                       float* fU, float* fI,
                       unsigned short* gU, unsigned short* gI,
                       int* deg, float* acc,
                       float* __restrict__ regp) {
  __shared__ float red[4];
  int t = blockIdx.x * 256 + threadIdx.x;  // t in [0, N_TOT*16)
  if (t < 20) acc[t] = (t >= 8 && t < 16) ? -INFINITY : 0.f;
  if (t < N_I) deg[t] = 0;
  int n = t >> 4, q = t & 15;
  float s = 0.f;
  if (n < N_U) {
    float4 v = ((const float4*)Eu0)[t];
    ((float4*)(fU + (size_t)n * 128))[q] = v;
    uint4 gv = {(unsigned)f2bf(v.x), (unsigned)f2bf(v.y), (unsigned)f2bf(v.z), (unsigned)f2bf(v.w)};
    ((uint4*)(gU + (size_t)n * 128))[q] = gv;
    s = v.x * v.x + v.y * v.y + v.z * v.z + v.w * v.w;
  } else if (n < N_TOT) {
    int j = t - N_U * 16;
    int ni = n - N_U;
    float4 v = ((const float4*)Ei0)[j];
    ((float4*)(fI + (size_t)ni * 128))[q] = v;
    uint4 gv = {(unsigned)f2bf(v.x), (unsigned)f2bf(v.y), (unsigned)f2bf(v.z), (unsigned)f2bf(v.w)};
    ((uint4*)(gI + (size_t)ni * 128))[q] = gv;
    s = v.x * v.x + v.y * v.y + v.z * v.z + v.w * v.w;
  }
  s = wred(s);
  int lane = threadIdx.x & 63, wv = threadIdx.x >> 6;
  if (lane == 0) red[wv] = s;
  __syncthreads();
  if (threadIdx.x == 0)
    regp[blockIdx.x] = red[0] + red[1] + red[2] + red[3];
}

// ---------------- CSR build over item side ----------------
__global__ void k_deg(const int* __restrict__ ii, int* deg) {
  int e = blockIdx.x * 256 + threadIdx.x;
  if (e < NNZ) atomicAdd(&deg[ii[e]], 1);
}

// shuffle-based scan: 2 barriers, deg cached in registers (bit-exact int ops)
__global__ void k_scan(const int* __restrict__ deg, int* rowptr, int* cursor) {
  __shared__ int wtot[16], woff[16];
  const int CHUNK = 15;
  int tid = threadIdx.x, lane = tid & 63, wv = tid >> 6;
  int base = tid * CHUNK;
  int dv[CHUNK];
  int s = 0;
#pragma unroll
  for (int k = 0; k < CHUNK; k++) {
    int idx = base + k;
    dv[k] = (idx < N_I) ? deg[idx] : 0;
    s += dv[k];
  }
  int v = s;
#pragma unroll
  for (int o = 1; o < 64; o <<= 1) {
    int x = __shfl_up(v, o, 64);
    if (lane >= o) v += x;
  }
  if (lane == 63) wtot[wv] = v;
  __syncthreads();
  if (tid < 16) {
    int w = wtot[tid];
    int iv = w;
#pragma unroll
    for (int o = 1; o < 16; o <<= 1) {
      int x = __shfl_up(iv, o, 16);
      if (tid >= o) iv += x;
    }
    woff[tid] = iv - w;
  }
  __syncthreads();
  int excl = (v - s) + woff[wv];
#pragma unroll
  for (int k = 0; k < CHUNK; k++) {
    int idx = base + k;
    if (idx < N_I) {
      rowptr[idx] = excl;
      cursor[idx] = excl;
      excl += dv[k];
    }
  }
  if (tid == 1023) rowptr[N_I] = excl;
}

__global__ void k_fill(const int* __restrict__ ii, const float* __restrict__ vals,
                       int* cursor, int* u_srt, float* v_srt) {
  int e = blockIdx.x * 256 + threadIdx.x;
  if (e < NNZ) {
    int pos = atomicAdd(&cursor[ii[e]], 1);
    u_srt[pos] = e >> 4;
    v_srt[pos] = vals[e];
  }
}

// ---------------- GAT: feat = E @ W into fused[64:128] (fp32) + interleaved bf16 mirror, el/er ----------------
__global__ void k_feat(float* __restrict__ fU, float* __restrict__ fI,
                       unsigned short* __restrict__ gU, unsigned short* __restrict__ gI,
                       const float* __restrict__ W, const float* __restrict__ al,
                       const float* __restrict__ ar,
                       float* __restrict__ el, float* __restrict__ er) {
  __shared__ float Ws[64 * 64];
  __shared__ float hs[16][64];
  int tid = threadIdx.x;
  for (int t = tid; t < 1024; t += 256) ((float4*)Ws)[t] = ((const float4*)W)[t];
  int g = tid >> 6, c = tid & 63;
  int n0 = blockIdx.x * 16 + g * 4;
  float* rows[4];
  unsigned short* grows[4];
#pragma unroll
  for (int j = 0; j < 4; j++) {
    int node = n0 + j;
    rows[j] = nullptr; grows[j] = nullptr;
    if (node < N_TOT) {
      if (node < N_U) {
        rows[j] = fU + (size_t)node * 128;
        grows[j] = gU + (size_t)node * 128;
      } else {
        rows[j] = fI + (size_t)(node - N_U) * 128;
        grows[j] = gI + (size_t)(node - N_U) * 128;
      }
      hs[g * 4 + j][c] = rows[j][c];
    }
  }
  __syncthreads();
  float a0 = 0.f, a1 = 0.f, a2 = 0.f, a3 = 0.f;
#pragma unroll 8
  for (int k = 0; k < 64; ++k) {
    float w = Ws[k * 64 + c];
    a0 = fmaf(hs[g * 4 + 0][k], w, a0);
    a1 = fmaf(hs[g * 4 + 1][k], w, a1);
    a2 = fmaf(hs[g * 4 + 2][k], w, a2);
    a3 = fmaf(hs[g * 4 + 3][k], w, a3);
  }
  float accs[4] = {a0, a1, a2, a3};
  float alc = al[c], arc = ar[c];
#pragma unroll
  for (int j = 0; j < 4; j++) {
    int node = n0 + j;
    if (node >= N_TOT) continue;
    rows[j][64 + c] = accs[j];
    grows[j][2 * c + 1] = f2bf(accs[j]);
    float pl = accs[j] * alc;
    float pr = accs[j] * arc;
#pragma unroll
    for (int o = 8; o >= 1; o >>= 1) {
      pl += __shfl_down(pl, o, 16);
      pr += __shfl_down(pr, o, 16);
    }
    if ((c & 15) == 0) {
      el[node * 4 + (c >> 4)] = pl;
      er[node * 4 + (c >> 4)] = pr;
    }
  }
}

// ---------------- per-head global max of el (separate kernel: few atomics; r7 lesson) ----------------
__global__ void k_elmax(const float* __restrict__ el, float* __restrict__ dst) {
  __shared__ float red[4][4];
  int tid = threadIdx.x;
  int lane = tid & 63, wv = tid >> 6;
  float mx = -INFINITY;
  for (int t = blockIdx.x * 256 + tid; t < N_TOT * 4; t += 64 * 256)
    mx = fmaxf(mx, el[t]);
#pragma unroll
  for (int o = 4; o < 64; o <<= 1) mx = fmaxf(mx, __shfl_xor(mx, o, 64));
  if (lane < 4) red[wv][lane] = mx;
  __syncthreads();
  if (tid < 4) {
    float m2 = fmaxf(fmaxf(red[0][tid], red[1][tid]), fmaxf(red[2][tid], red[3][tid]));
    atomMaxF(dst + tid, m2);
  }
}

// ---------------- fused graph layer ----------------
// r10: exp-dedup via shfl + interleaved-mirror gathers.
// r13: deferred sE — last layer computes s_final=(E0+selfrow)+e_new (bit-exact).
// r14: deferred sG — layer1 stores g1; last layer sG=(E0+g1)+g2; dead-store elim on last layer.
__global__ void k_layer(const float* __restrict__ fU_cur, const float* __restrict__ fI_cur,
                        const unsigned short* __restrict__ gU_cur,
                        const unsigned short* __restrict__ gI_cur,
                        const float* __restrict__ el, const float* __restrict__ er,
                        const float* __restrict__ vals, const int* __restrict__ ii,
                        const int* __restrict__ rowptr, const int* __restrict__ u_srt,
                        const float* __restrict__ v_srt,
                        const float* __restrict__ elmx,
                        const float* __restrict__ E0u, const float* __restrict__ E0i,
                        float* __restrict__ fU_nxt, float* __restrict__ fI_nxt,
                        unsigned short* __restrict__ gU_nxt, unsigned short* __restrict__ gI_nxt,
                        float* __restrict__ sEu, float* __restrict__ sEi,
                        float* __restrict__ sGu, float* __restrict__ sGi,
                        unsigned short* __restrict__ EuH, unsigned short* __restrict__ EuL,
                        unsigned short* __restrict__ EiH, unsigned short* __restrict__ EiL,
                        float* __restrict__ normU, float* __restrict__ normI) {
  int t = blockIdx.x * 256 + threadIdx.x;
  int node = t >> 6, c = t & 63;
  if (node >= N_TOT) return;
  int h = c >> 4;
  int k2 = c & 15;

  if (node < N_U) {
    int u = node;
    float eru = er[u * 4 + h];
    float m = leaky(elmx[h] + eru);
    const float* selfrow = fU_cur + (size_t)u * 128;
    float aself = __expf(leaky(el[u * 4 + h] + eru) - m);

    int idx[16]; float vv[16];
#pragma unroll
    for (int k = 0; k < 16; k++) { idx[k] = ii[u * 16 + k]; vv[k] = vals[u * 16 + k]; }

    float ev = __expf(leaky(el[(ii[u * 16 + k2] + N_U) * 4 + h] + eru) - m);
    float av[16];
#pragma unroll
    for (int k = 0; k < 16; k++)
      av[k] = __shfl(ev, (c & 48) | k, 64);

    float den = aself;
#pragma unroll
    for (int k = 0; k < 16; k++) den += av[k];

    float o0 = aself * selfrow[64 + c], o1 = 0.f;
    float z0 = 0.f, z1 = 0.f;
#pragma unroll
    for (int k = 0; k < 16; k += 2) {
      unsigned wA = *(const unsigned*)(gI_cur + (size_t)idx[k] * 128 + 2 * c);
      unsigned wB = *(const unsigned*)(gI_cur + (size_t)idx[k + 1] * 128 + 2 * c);
      float eA = __uint_as_float(wA << 16), fA = __uint_as_float(wA & 0xFFFF0000u);
      float eB = __uint_as_float(wB << 16), fB = __uint_as_float(wB & 0xFFFF0000u);
      z0 = fmaf(vv[k], eA, z0);
      z1 = fmaf(vv[k + 1], eB, z1);
      o0 = fmaf(av[k], fA, o0);
      o1 = fmaf(av[k + 1], fB, o1);
    }
    float o = (o0 + o1) / den;
    float g = (o > 0.f) ? o : expm1f(o);
    float e_new = selfrow[c] + z0 + z1;
    size_t off = (size_t)u * D + c;
    if (EuH) {
      float e0v = E0u[off];
      float s_final = (e0v + selfrow[c]) + e_new;
      sEu[off] = s_final;
      sGu[off] = (e0v + sGu[off]) + g;
      unsigned short hi = f2bf(s_final);
      EuH[off] = hi;
      EuL[off] = f2bf(s_final - bf2f(hi));
      float n2 = wred(s_final * s_final);
      if (c == 0) normU[u] = n2;
    } else {
      fU_nxt[(size_t)u * 128 + c] = e_new;
      gU_nxt[(size_t)u * 128 + 2 * c] = f2bf(e_new);
      sGu[off] = g;
    }
  } else {
    int i = node - N_U;
    float eri = er[node * 4 + h];
    float m = leaky(elmx[h] + eri);
    const float* selfrow = fI_cur + (size_t)i * 128;
    float aself = __expf(leaky(el[node * 4 + h] + eri) - m);
    float den0 = aself, den1 = 0.f;
    float o0 = aself * selfrow[64 + c], o1 = 0.f;
    float z0 = 0.f, z1 = 0.f;
    int r0 = rowptr[i], r1 = rowptr[i + 1];
    for (int rb = r0; rb < r1; rb += 16) {
      int cnt = min(16, r1 - rb);
      int rr = rb + (k2 < cnt ? k2 : cnt - 1);
      float ev = __expf(leaky(el[u_srt[rr] * 4 + h] + eri) - m);
      int k = 0;
      for (; k + 3 < cnt; k += 4) {
        int u0 = u_srt[rb + k], u1 = u_srt[rb + k + 1], u2 = u_srt[rb + k + 2], u3 = u_srt[rb + k + 3];
        float v0 = v_srt[rb + k], v1 = v_srt[rb + k + 1], v2 = v_srt[rb + k + 2], v3 = v_srt[rb + k + 3];
        float a0 = __shfl(ev, (c & 48) | k, 64);
        float a1 = __shfl(ev, (c & 48) | (k + 1), 64);
        float a2 = __shfl(ev, (c & 48) | (k + 2), 64);
        float a3 = __shfl(ev, (c & 48) | (k + 3), 64);
        unsigned w0 = *(const unsigned*)(gU_cur + (size_t)u0 * 128 + 2 * c);
        unsigned w1 = *(const unsigned*)(gU_cur + (size_t)u1 * 128 + 2 * c);
        unsigned w2 = *(const unsigned*)(gU_cur + (size_t)u2 * 128 + 2 * c);
        unsigned w3 = *(const unsigned*)(gU_cur + (size_t)u3 * 128 + 2 * c);
        float e0 = __uint_as_float(w0 << 16), f0 = __uint_as_float(w0 & 0xFFFF0000u);
        float e1 = __uint_as_float(w1 << 16), f1 = __uint_as_float(w1 & 0xFFFF0000u);
        float e2 = __uint_as_float(w2 << 16), f2 = __uint_as_float(w2 & 0xFFFF0000u);
        float e3 = __uint_as_float(w3 << 16), f3 = __uint_as_float(w3 & 0xFFFF0000u);
        z0 = fmaf(v0, e0, z0); z1 = fmaf(v1, e1, z1);
        z0 = fmaf(v2, e2, z0); z1 = fmaf(v3, e3, z1);
        den0 += a0 + a2; den1 += a1 + a3;
        o0 = fmaf(a0, f0, o0); o1 = fmaf(a1, f1, o1);
        o0 = fmaf(a2, f2, o0); o1 = fmaf(a3, f3, o1);
      }
      for (; k < cnt; k++) {
        int u0 = u_srt[rb + k];
        float v0 = v_srt[rb + k];
        float a0 = __shfl(ev, (c & 48) | k, 64);
        unsigned w0 = *(const unsigned*)(gU_cur + (size_t)u0 * 128 + 2 * c);
        float e0 = __uint_as_float(w0 << 16), f0 = __uint_as_float(w0 & 0xFFFF0000u);
        z0 = fmaf(v0, e0, z0);
        den0 += a0;
        o0 = fmaf(a0, f0, o0);
      }
    }
    float o = (o0 + o1) / (den0 + den1);
    float g = (o > 0.f) ? o : expm1f(o);
    float e_new = selfrow[c] + z0 + z1;
    size_t off = (size_t)i * D + c;
    if (EiH) {
      float e0v = E0i[off];
      float s_final = (e0v + selfrow[c]) + e_new;
      sEi[off] = s_final;
      sGi[off] = (e0v + sGi[off]) + g;
      unsigned short hi = f2bf(s_final);
      EiH[off] = hi;
      EiL[off] = f2bf(s_final - bf2f(hi));
      float n2 = wred(s_final * s_final);
      if (c == 0) normI[i] = n2;
    } else {
      fI_nxt[(size_t)i * 128 + c] = e_new;
      gI_nxt[(size_t)i * 128 + 2 * c] = f2bf(e_new);
      sGi[off] = g;
    }
  }
}

// ---------------- max row-norm reduce + L2 reg reduce (reads per-block partials from k_init) ----------------
__global__ void k_normreg(const float* __restrict__ nU, const float* __restrict__ nI,
                          const float* __restrict__ regp,
                          float* __restrict__ acc) {
  __shared__ float red[4][3];
  int tid = threadIdx.x;
  int lane = tid & 63, wv = tid >> 6;
  float mu = 0.f, mi = 0.f, s = 0.f;
  for (int t = blockIdx.x * 256 + tid; t < N_U; t += 128 * 256) mu = fmaxf(mu, nU[t]);
  for (int t = blockIdx.x * 256 + tid; t < N_I; t += 128 * 256) mi = fmaxf(mi, nI[t]);
  for (int t = blockIdx.x * 256 + tid; t < NREGP; t += 128 * 256) s += regp[t];
#pragma unroll
  for (int o = 32; o > 0; o >>= 1) {
    mu = fmaxf(mu, __shfl_down(mu, o, 64));
    mi = fmaxf(mi, __shfl_down(mi, o, 64));
    s += __shfl_down(s, o, 64);
  }
  if (lane == 0) { red[wv][0] = mu; red[wv][1] = mi; red[wv][2] = s; }
  __syncthreads();
  if (tid == 0) {
    float a = fmaxf(fmaxf(red[0][0], red[1][0]), fmaxf(red[2][0], red[3][0]));
    float b = fmaxf(fmaxf(red[0][1], red[1][1]), fmaxf(red[2][1], red[3][1]));
    float ssum = red[0][2] + red[1][2] + red[2][2] + red[3][2];
    atomMaxF(acc + 6, a);
    atomMaxF(acc + 7, b);
    unsafeAtomicAdd(acc + 5, ssum);
  }
}

// ---------------- gathered queries: pre-scaled split-bf16 + Cauchy-Schwarz offset M0 ----------------
__global__ void k_cvt_q(const float* __restrict__ sGu, const float* __restrict__ sGi,
                        const int* __restrict__ uids, const int* __restrict__ iids,
                        unsigned short* __restrict__ QuH, unsigned short* __restrict__ QuL,
                        unsigned short* __restrict__ QiH, unsigned short* __restrict__ QiL,
                        const float* __restrict__ acc,
                        float* __restrict__ M0u, float* __restrict__ M0i) {
  int lane = threadIdx.x & 63, wv = threadIdx.x >> 6;
  int row = blockIdx.x * 4 + wv;
  int side = row >> 11;
  int b = row & (B - 1);
  int id = side ? iids[b] : uids[b];
  float x = (side ? sGi : sGu)[(size_t)id * 64 + lane] * SCALE_LOG2;
  unsigned short hi = f2bf(x);
  unsigned short lo = f2bf(x - bf2f(hi));
  if (side) { QiH[(size_t)b * 64 + lane] = hi; QiL[(size_t)b * 64 + lane] = lo; }
  else      { QuH[(size_t)b * 64 + lane] = hi; QuL[(size_t)b * 64 + lane] = lo; }
  float n2 = wred(x * x);
  if (lane == 0) {
    float en2 = side ? acc[7] : acc[6];
    float M0 = sqrtf(n2) * sqrtf(en2) * 1.01f + 1.0f;
    (side ? M0i : M0u)[b] = M0;
  }
}

// ---------------- MFMA logsumexp: r15-exact (empirical optimum, 48.5us) ----------------
// (256,2)+t=8+depth-1 register-locked; NSP=64 -> 512 blocks single residency wave.
__global__ __launch_bounds__(256, 2) void k_lse_mfma(
    const unsigned short* __restrict__ QuH, const unsigned short* __restrict__ QuL,
    const unsigned short* __restrict__ EuHp, const unsigned short* __restrict__ EuLp,
    const unsigned short* __restrict__ QiH, const unsigned short* __restrict__ QiL,
    const unsigned short* __restrict__ EiHp, const unsigned short* __restrict__ EiLp,
    const float* __restrict__ M0u, const float* __restrict__ M0i,
    float* __restrict__ psU, float* __restrict__ psI) {
  int z = blockIdx.z;
  const unsigned short* Qhi = z ? QiH : QuH;
  const unsigned short* Qlo = z ? QiL : QuL;
  const unsigned short* Ehi = z ? EiHp : EuHp;
  const unsigned short* Elo = z ? EiLp : EuLp;
  const float* M0arr = z ? M0i : M0u;
  float* part_s = z ? psI : psU;
  int n_rows = z ? N_I : N_U;
  int rows_per_split = z ? RSP_I : RSP_U;

  int tid = threadIdx.x;
  int wave = tid >> 6, lane = tid & 63;
  int l15 = lane & 15, quad = lane >> 4;
  int qbase = (blockIdx.x * 4 + wave) * 128;
  int split = blockIdx.y;
  int row0 = split * rows_per_split;
  int row_end = min(row0 + rows_per_split, n_rows);
  int rows = row_end - row0; if (rows < 0) rows = 0;
  int total = (rows + 15) >> 4;
  int ntail = rows & 15;

  float ss[8][4];
#pragma unroll
  for (int t = 0; t < 8; t++)
#pragma unroll
    for (int g = 0; g < 4; g++) ss[t][g] = 0.f;

  if (total > 0) {
    short8 ah[8][2], al[8][2];
#pragma unroll
    for (int t = 0; t < 8; t++)
#pragma unroll
      for (int c = 0; c < 2; c++) {
        size_t idx = (size_t)(qbase + t * 16 + l15) * 64 + c * 32 + quad * 8;
        ah[t][c] = *(const short8*)(Qhi + idx);
        al[t][c] = *(const short8*)(Qlo + idx);
      }

    f32x4 cinit[8];
#pragma unroll
    for (int t = 0; t < 8; t++)
#pragma unroll
      for (int g = 0; g < 4; g++)
        cinit[t][g] = -M0arr[qbase + t * 16 + quad * 4 + g];

    const unsigned short* ph = Ehi + (size_t)(row0 + l15) * 64 + quad * 8;
    const unsigned short* pl = Elo + (size_t)(row0 + l15) * 64 + quad * 8;

    short8 cb0 = *(const short8*)(ph);
    short8 cb1 = *(const short8*)(ph + 32);
    short8 cb2 = *(const short8*)(pl);
    short8 cb3 = *(const short8*)(pl + 32);
    ph += 1024; pl += 1024;

    for (int it = 0; it < total - 1; it++) {
      short8 nb0 = *(const short8*)(ph);
      short8 nb1 = *(const short8*)(ph + 32);
      short8 nb2 = *(const short8*)(pl);
      short8 nb3 = *(const short8*)(pl + 32);
      ph += 1024; pl += 1024;
#pragma unroll
      for (int t = 0; t < 8; t++) {
        f32x4 acc = cinit[t];
        acc = __builtin_amdgcn_mfma_f32_16x16x32_bf16(ah[t][0], cb0, acc, 0, 0, 0);
        acc = __builtin_amdgcn_mfma_f32_16x16x32_bf16(ah[t][1], cb1, acc, 0, 0, 0);
        acc = __builtin_amdgcn_mfma_f32_16x16x32_bf16(al[t][0], cb0, acc, 0, 0, 0);
        acc = __builtin_amdgcn_mfma_f32_16x16x32_bf16(al[t][1], cb1, acc, 0, 0, 0);
        acc = __builtin_amdgcn_mfma_f32_16x16x32_bf16(ah[t][0], cb2, acc, 0, 0, 0);
        acc = __builtin_amdgcn_mfma_f32_16x16x32_bf16(ah[t][1], cb3, acc, 0, 0, 0);
#pragma unroll
        for (int g = 0; g < 4; g++)
          ss[t][g] += exp2f(acc[g]);
      }
      cb0 = nb0; cb1 = nb1; cb2 = nb2; cb3 = nb3;
    }
    {
      bool valid = (ntail == 0) || (l15 < ntail);
#pragma unroll
      for (int t = 0; t < 8; t++) {
        f32x4 acc = cinit[t];
        acc = __builtin_amdgcn_mfma_f32_16x16x32_bf16(ah[t][0], cb0, acc, 0, 0, 0);
        acc = __builtin_amdgcn_mfma_f32_16x16x32_bf16(ah[t][1], cb1, acc, 0, 0, 0);
        acc = __builtin_amdgcn_mfma_f32_16x16x32_bf16(al[t][0], cb0, acc, 0, 0, 0);
        acc = __builtin_amdgcn_mfma_f32_16x16x32_bf16(al[t][1], cb1, acc, 0, 0, 0);
        acc = __builtin_amdgcn_mfma_f32_16x16x32_bf16(ah[t][0], cb2, acc, 0, 0, 0);
        acc = __builtin_amdgcn_mfma_f32_16x16x32_bf16(ah[t][1], cb3, acc, 0, 0, 0);
#pragma unroll
        for (int g = 0; g < 4; g++) {
          float e = exp2f(acc[g]);
          ss[t][g] += valid ? e : 0.f;
        }
      }
    }
  }

#pragma unroll
  for (int off = 1; off < 16; off <<= 1) {
#pragma unroll
    for (int t = 0; t < 8; t++)
#pragma unroll
      for (int g = 0; g < 4; g++)
        ss[t][g] += __shfl_xor(ss[t][g], off, 64);
  }

  if (l15 == 0) {
#pragma unroll
    for (int t = 0; t < 8; t++)
#pragma unroll
      for (int g = 0; g < 4; g++) {
        int q = qbase + t * 16 + quad * 4 + g;
        part_s[(size_t)split * B + q] = ss[t][g];
      }
  }
}

// ---------------- per-sample losses + fused finalize (8-block ticket, uncontended) ----------------
__global__ void k_small(const float* __restrict__ sEu, const float* __restrict__ sEi,
                        const float* __restrict__ sGu, const float* __restrict__ sGi,
                        const int* __restrict__ uids, const int* __restrict__ iids,
                        const int* __restrict__ pos, const int* __restrict__ neg,
                        const float* __restrict__ psU, const float* __restrict__ psI,
                        const float* __restrict__ M0u, const float* __restrict__ M0i,
                        float* acc, float* __restrict__ out) {
  int b = blockIdx.x * 256 + threadIdx.x;
  float du = 0.f, di = 0.f, nu = 0.f, ni = 0.f, bpr = 0.f;
  if (b < B) {
    float su = 0.f, si = 0.f;
    for (int s2 = 0; s2 < NSP; s2++) su += psU[(size_t)s2 * B + b];
    for (int s2 = 0; s2 < NSP; s2++) si += psI[(size_t)s2 * B + b];
    float lseu = M0u[b] * LN2F + logf(su);
    float lsei = M0i[b] * LN2F + logf(si);
    nu = fmaxf(lseu, LOG_EPS) + log1pf(expf(-fabsf(lseu - LOG_EPS)));
    ni = fmaxf(lsei, LOG_EPS) + log1pf(expf(-fabsf(lsei - LOG_EPS)));

    int u = uids[b], it = iids[b], p = pos[b], ng = neg[b];
    const float4* gu = (const float4*)(sGu + (size_t)u * D);
    const float4* eu = (const float4*)(sEu + (size_t)u * D);
    const float4* gi = (const float4*)(sGi + (size_t)it * D);
    const float4* ei = (const float4*)(sEi + (size_t)it * D);
    const float4* ep = (const float4*)(sEi + (size_t)p * D);
    const float4* en = (const float4*)(sEi + (size_t)ng * D);
    float diff = 0.f;
#pragma unroll
    for (int k = 0; k < 16; k++) {
      float4 a = gu[k], b4 = eu[k];
      du += a.x * b4.x + a.y * b4.y + a.z * b4.z + a.w * b4.w;
      float4 c = gi[k], d4 = ei[k];
      di += c.x * d4.x + c.y * d4.y + c.z * d4.z + c.w * d4.w;
      float4 e = ep[k], f = en[k];
      diff += b4.x * (e.x - f.x) + b4.y * (e.y - f.y) + b4.z * (e.z - f.z) + b4.w * (e.w - f.w);
    }
    bpr = (diff > 0.f) ? log1pf(expf(-diff)) : (-diff + log1pf(expf(diff)));
  }
  du = wred(du); di = wred(di); nu = wred(nu); ni = wred(ni); bpr = wred(bpr);
  if ((threadIdx.x & 63) == 0) {
    unsafeAtomicAdd(acc + 0, du);
    unsafeAtomicAdd(acc + 1, di);
    unsafeAtomicAdd(acc + 2, nu);
    unsafeAtomicAdd(acc + 3, ni);
    unsafeAtomicAdd(acc + 4, bpr);
  }
  __syncthreads();
  if (threadIdx.x == 0) {
    __threadfence();
    int ticket = atomicAdd((int*)(acc + 16), 1);
    if (ticket == (int)gridDim.x - 1) {
      __threadfence();
      float a0 = unsafeAtomicAdd(acc + 0, 0.f);
      float a1 = unsafeAtomicAdd(acc + 1, 0.f);
      float a2 = unsafeAtomicAdd(acc + 2, 0.f);
      float a3 = unsafeAtomicAdd(acc + 3, 0.f);
      float a4 = unsafeAtomicAdd(acc + 4, 0.f);
      float a5 = unsafeAtomicAdd(acc + 5, 0.f);
      float pos_score = (a0 + a1) * (INV_TEMP / (float)B);
      float neg_score = (a2 + a3) / (float)B;
      float loss_s = neg_score - pos_score;
      float loss_r = a4 / (float)B;
      float reg = LAMBDA2 * a5;
      out[0] = loss_r + LAMBDA1 * loss_s + reg;
      out[1] = loss_r;
      out[2] = LAMBDA1 * loss_s;
    }
  }
}

extern "C" void kernel_launch(void* const* d_in, const int* in_sizes, int n_in,
                              void* d_out, int out_size, void* d_ws, size_t ws_size,
                              hipStream_t stream) {
  const float* Eu0  = (const float*)d_in[0];
  const float* Ei0  = (const float*)d_in[1];
  const float* vals = (const float*)d_in[2];
  const float* W    = (const float*)d_in[3];
  const float* al   = (const float*)d_in[4];
  const float* ar   = (const float*)d_in[5];
  const int* ii     = (const int*)d_in[7];
  const int* uids   = (const int*)d_in[10];
  const int* iids   = (const int*)d_in[11];
  const int* pos    = (const int*)d_in[12];
  const int* neg    = (const int*)d_in[13];
  float* out = (float*)d_out;

  char* base = (char*)d_ws;
  size_t off = 0;
  auto alloc = [&](size_t bytes) -> void* {
    void* p = base + off;
    off = (off + bytes + 255) & ~(size_t)255;
    return p;
  };
  float* fU_a = (float*)alloc((size_t)N_U * 128 * 4);
  float* fU_b = (float*)alloc((size_t)N_U * 128 * 4);
  float* fI_a = (float*)alloc((size_t)N_I * 128 * 4);
  float* fI_b = (float*)alloc((size_t)N_I * 128 * 4);
  unsigned short* gU_a = (unsigned short*)alloc((size_t)N_U * 128 * 2);
  unsigned short* gU_b = (unsigned short*)alloc((size_t)N_U * 128 * 2);
  unsigned short* gI_a = (unsigned short*)alloc((size_t)N_I * 128 * 2);
  unsigned short* gI_b = (unsigned short*)alloc((size_t)N_I * 128 * 2);
  float* sEu  = (float*)alloc((size_t)N_U * D * 4);
  float* sEi  = (float*)alloc((size_t)N_I * D * 4);
  float* sGu  = (float*)alloc((size_t)N_U * D * 4);
  float* sGi  = (float*)alloc((size_t)N_I * D * 4);
  float* el   = (float*)alloc((size_t)N_TOT * 4 * 4);
  float* er   = (float*)alloc((size_t)N_TOT * 4 * 4);
  float* psU  = (float*)alloc((size_t)B * NSP * 4);
  float* psI  = (float*)alloc((size_t)B * NSP * 4);
  float* M0u  = (float*)alloc((size_t)B * 4);
  float* M0i  = (float*)alloc((size_t)B * 4);
  float* normU= (float*)alloc((size_t)N_U * 4);
  float* normI= (float*)alloc((size_t)N_I * 4);
  float* acc  = (float*)alloc(32 * 4);
  float* regp = (float*)alloc((size_t)NREGP * 4);
  int* deg    = (int*)alloc((size_t)N_I * 4);
  int* cursor = (int*)alloc((size_t)N_I * 4);
  int* rowptr = (int*)alloc((size_t)(N_I + 1) * 4);
  int* u_srt  = (int*)alloc((size_t)NNZ * 4);
  float* v_srt= (float*)alloc((size_t)NNZ * 4);
  unsigned short* EuH = (unsigned short*)alloc((size_t)PAD_U * 64 * 2);
  unsigned short* EuL = (unsigned short*)alloc((size_t)PAD_U * 64 * 2);
  unsigned short* EiH = (unsigned short*)alloc((size_t)PAD_I * 64 * 2);
  unsigned short* EiL = (unsigned short*)alloc((size_t)PAD_I * 64 * 2);
  unsigned short* QuH = (unsigned short*)alloc((size_t)B * 64 * 2);
  unsigned short* QuL = (unsigned short*)alloc((size_t)B * 64 * 2);
  unsigned short* QiH = (unsigned short*)alloc((size_t)B * 64 * 2);
  unsigned short* QiL = (unsigned short*)alloc((size_t)B * 64 * 2);

  k_init<<<NREGP, 256, 0, stream>>>(Eu0, Ei0, fU_a, fI_a, gU_a, gI_a,
                                    deg, acc, regp);
  k_deg<<<(NNZ + 255) / 256, 256, 0, stream>>>(ii, deg);
  k_scan<<<1, 1024, 0, stream>>>(deg, rowptr, cursor);
  k_fill<<<(NNZ + 255) / 256, 256, 0, stream>>>(ii, vals, cursor, u_srt, v_srt);

  float* cu = fU_a; float* ci = fI_a;
  float* nu = fU_b; float* ni = fI_b;
  unsigned short* gcu = gU_a; unsigned short* gci = gI_a;
  unsigned short* gnu = gU_b; unsigned short* gni = gI_b;
  for (int l = 0; l < 2; ++l) {
    float* elmx = acc + 8 + 4 * l;
    bool last = (l == 1);
    k_feat<<<(N_TOT + 15) / 16, 256, 0, stream>>>(cu, ci, gcu, gci, W, al, ar, el, er);
    k_elmax<<<64, 256, 0, stream>>>(el, elmx);
    k_layer<<<(N_TOT * D) / 256, 256, 0, stream>>>(
        cu, ci, gcu, gci, el, er, vals, ii, rowptr, u_srt, v_srt, elmx,
        Eu0, Ei0,
        nu, ni, gnu, gni, sEu, sEi, sGu, sGi,
        last ? EuH : nullptr, last ? EuL : nullptr,
        last ? EiH : nullptr, last ? EiL : nullptr,
        normU, normI);
    float* t1 = cu; cu = nu; nu = t1;
    float* t2 = ci; ci = ni; ni = t2;
    unsigned short* t3 = gcu; gcu = gnu; gnu = t3;
    unsigned short* t4 = gci; gci = gni; gni = t4;
  }

  k_normreg<<<128, 256, 0, stream>>>(normU, normI, regp, acc);
  k_cvt_q<<<(2 * B) / 4, 256, 0, stream>>>(sGu, sGi, uids, iids, QuH, QuL, QiH, QiL, acc, M0u, M0i);
  k_lse_mfma<<<dim3(B / 512, NSP, 2), 256, 0, stream>>>(QuH, QuL, EuH, EuL,
                                                        QiH, QiL, EiH, EiL,
                                                        M0u, M0i, psU, psI);
  k_small<<<B / 256, 256, 0, stream>>>(sEu, sEi, sGu, sGi, uids, iids, pos, neg,
                                       psU, psI, M0u, M0i, acc, out);
}